// Round 8
// baseline (1252.022 us; speedup 1.0000x reference)
//
#include <hip/hip_runtime.h>

// ---------------------------------------------------------------------------
// TAGCN node regression: 3 TAGConv layers (K=4) + linear head, fp32 math.
// CSR-by-dst built once per launch (rank from the degree atomic; fill has no
// atomics). Propagation fused with matmul accumulation; F=64 kernel: 20480 B
// LDS (8 blocks/CU), 28-VGPR scalar-broadcast mm loop. Inter-dispatch h in
// BF16 (R7). R8: 4-edge-unrolled gather (deeper MLP), nontemporal ep loads
// (stop ep stream from evicting the h working set in L2), cvt fused into
// degcount. Atomic floor measured ~0.73 TB/s write-through -> degcount ~150us
// is structural.
// ---------------------------------------------------------------------------

typedef unsigned long long u64;
typedef int iv4 __attribute__((ext_vector_type(4)));

__device__ __forceinline__ float bf2f(unsigned short u) {
  return __uint_as_float(((unsigned int)u) << 16);
}
__device__ __forceinline__ unsigned short f2bf(float f) {
  unsigned int u = __float_as_uint(f);
  u += 0x7FFF + ((u >> 16) & 1);  // round to nearest even
  return (unsigned short)(u >> 16);
}
__device__ __forceinline__ ushort4 pack_bf(float4 v) {
  ushort4 r;
  r.x = f2bf(v.x); r.y = f2bf(v.y); r.z = f2bf(v.z); r.w = f2bf(v.w);
  return r;
}
// nontemporal 16B load of two packed edges
__device__ __forceinline__ iv4 nt_ep2(const int2* p) {
  return __builtin_nontemporal_load((const iv4*)p);
}

// one 64-bit atomic per edge: [count:16 | sum_w Q16.32 fixed point:48]
// + fused x->bf16 convert (independent work, saves a dispatch)
__global__ void degcount_k(const int* __restrict__ dst, const float* __restrict__ w,
                           u64* __restrict__ pack, int* __restrict__ rank, int E,
                           const float4* __restrict__ x4, ushort4* __restrict__ xb, int n4) {
  int e = blockIdx.x * blockDim.x + threadIdx.x;
  if (e < n4) xb[e] = pack_bf(x4[e]);
  if (e >= E) return;
  int d = dst[e];
  u64 v = ((u64)1 << 48) | (u64)((double)w[e] * 4294967296.0);
  u64 old = atomicAdd(&pack[d], v);
  rank[e] = (int)(old >> 48);
}

// scan (256/block) fused with degree decode -> dinv
__global__ void scan_blocks(const u64* __restrict__ pack, float* __restrict__ dinv,
                            int* __restrict__ ptr, int* __restrict__ bsum, int n) {
  __shared__ int s[256];
  int tid = threadIdx.x;
  int i = blockIdx.x * 256 + tid;
  int v = 0;
  if (i < n) {
    u64 p = pack[i];
    v = (int)(p >> 48);
    float d = (float)((double)(p & 0xFFFFFFFFFFFFULL) * (1.0 / 4294967296.0));
    dinv[i] = (d > 0.f) ? rsqrtf(fmaxf(d, 1e-30f)) : 0.f;
  }
  s[tid] = v;
  __syncthreads();
#pragma unroll
  for (int off = 1; off < 256; off <<= 1) {
    int t = (tid >= off) ? s[tid - off] : 0;
    __syncthreads();
    s[tid] += t;
    __syncthreads();
  }
  if (i < n) ptr[i] = s[tid] - v;
  if (tid == 255) bsum[blockIdx.x] = s[255];
}

__global__ void scan_sums(int* __restrict__ bsum, int nb) {
  __shared__ int s[512];
  int tid = threadIdx.x;
  int v = (tid < nb) ? bsum[tid] : 0;
  s[tid] = v;
  __syncthreads();
#pragma unroll
  for (int off = 1; off < 512; off <<= 1) {
    int t = (tid >= off) ? s[tid - off] : 0;
    __syncthreads();
    s[tid] += t;
    __syncthreads();
  }
  if (tid < nb) bsum[tid] = s[tid] - v;
}

__global__ void scan_add(int* __restrict__ ptr, const int* __restrict__ bsum, int n, int E) {
  int i = blockIdx.x * blockDim.x + threadIdx.x;
  if (i < n) ptr[i] += bsum[i >> 8];
  if (i == 0) ptr[n] = E;
}

// scatter edges into CSR slots (atomic-free); payload = {src, folded norm}
__global__ void fill_k(const int* __restrict__ src, const int* __restrict__ dst,
                       const float* __restrict__ w, const float* __restrict__ dinv,
                       const int* __restrict__ ptr, const int* __restrict__ rank,
                       int2* __restrict__ ep, int E) {
  int e = blockIdx.x * blockDim.x + threadIdx.x;
  if (e >= E) return;
  int s = src[e], d = dst[e];
  float nv = dinv[s] * w[e] * dinv[d];
  int pos = ptr[d] + rank[e];
  ep[pos] = make_int2(s, __float_as_int(nv));
}

// gather t[f4] = sum_e w_e * bf2f(hin[src_e][f4]); 4-edge unrolled, nt ep loads
template <int F4>
__device__ __forceinline__ float4 gather(const int* __restrict__ ptr, const int2* __restrict__ ep,
                                         const ushort4* __restrict__ hin, int node, int f4) {
  int e0 = ptr[node], e1 = ptr[node + 1];
  float4 a = make_float4(0.f, 0.f, 0.f, 0.f);
  int e = e0;
  auto one = [&](int idx) {
    int2 p = ep[idx];
    float w0 = __int_as_float(p.y);
    ushort4 h = hin[(size_t)p.x * F4 + f4];
    a.x = fmaf(w0, bf2f(h.x), a.x); a.y = fmaf(w0, bf2f(h.y), a.y);
    a.z = fmaf(w0, bf2f(h.z), a.z); a.w = fmaf(w0, bf2f(h.w), a.w);
  };
  if ((e & 1) && e < e1) { one(e); ++e; }  // peel to even (16B-aligned pairs)
  for (; e + 3 < e1; e += 4) {             // 4 edges: 2x dwordx4 ep + 4 rows in flight
    iv4 p0 = nt_ep2(ep + e);
    iv4 p1 = nt_ep2(ep + e + 2);
    float w0 = __int_as_float(p0.y), w1 = __int_as_float(p0.w);
    float w2 = __int_as_float(p1.y), w3 = __int_as_float(p1.w);
    ushort4 h0 = hin[(size_t)p0.x * F4 + f4];
    ushort4 h1 = hin[(size_t)p0.z * F4 + f4];
    ushort4 h2 = hin[(size_t)p1.x * F4 + f4];
    ushort4 h3 = hin[(size_t)p1.z * F4 + f4];
    a.x = fmaf(w0, bf2f(h0.x), a.x); a.y = fmaf(w0, bf2f(h0.y), a.y);
    a.z = fmaf(w0, bf2f(h0.z), a.z); a.w = fmaf(w0, bf2f(h0.w), a.w);
    a.x = fmaf(w1, bf2f(h1.x), a.x); a.y = fmaf(w1, bf2f(h1.y), a.y);
    a.z = fmaf(w1, bf2f(h1.z), a.z); a.w = fmaf(w1, bf2f(h1.w), a.w);
    a.x = fmaf(w2, bf2f(h2.x), a.x); a.y = fmaf(w2, bf2f(h2.y), a.y);
    a.z = fmaf(w2, bf2f(h2.z), a.z); a.w = fmaf(w2, bf2f(h2.w), a.w);
    a.x = fmaf(w3, bf2f(h3.x), a.x); a.y = fmaf(w3, bf2f(h3.y), a.y);
    a.z = fmaf(w3, bf2f(h3.z), a.z); a.w = fmaf(w3, bf2f(h3.w), a.w);
  }
  if (e + 1 < e1) {  // remainder pair
    iv4 p = nt_ep2(ep + e);
    float w0 = __int_as_float(p.y), w1 = __int_as_float(p.w);
    ushort4 h0 = hin[(size_t)p.x * F4 + f4];
    ushort4 h1 = hin[(size_t)p.z * F4 + f4];
    a.x = fmaf(w0, bf2f(h0.x), a.x); a.y = fmaf(w0, bf2f(h0.y), a.y);
    a.z = fmaf(w0, bf2f(h0.z), a.z); a.w = fmaf(w0, bf2f(h0.w), a.w);
    a.x = fmaf(w1, bf2f(h1.x), a.x); a.y = fmaf(w1, bf2f(h1.y), a.y);
    a.z = fmaf(w1, bf2f(h1.z), a.z); a.w = fmaf(w1, bf2f(h1.w), a.w);
    e += 2;
  }
  if (e < e1) one(e);
  return a;
}

// scalar-broadcast mm accumulate: a += t(group ln) @ W  (28-VGPR shape, R6).
// t element i of group ln lives at word ln*64 + (((i>>2)^ln)<<2 | (i&3)).
__device__ __forceinline__ void mm_acc(const float* __restrict__ tl, const float4* __restrict__ Wl,
                                       int ln, int j4, float4& a) {
#pragma unroll 8
  for (int i = 0; i < 64; ++i) {
    float tv = tl[ln * 64 + ((((i >> 2) ^ ln) << 2) | (i & 3))];
    float4 wv = Wl[i * 16 + j4];
    a.x = fmaf(tv, wv.x, a.x); a.y = fmaf(tv, wv.y, a.y);
    a.z = fmaf(tv, wv.z, a.z); a.w = fmaf(tv, wv.w, a.w);
  }
}

// ---------- fused prop + matmul, F=64 (16 lanes/node, 16 nodes/block) ----------
// LDS = 16K W + 4K XOR-swizzled t tile = 20480 B -> 8 blocks/CU (VGPR <= ~50).
template <bool FIRST, bool LAST, bool HEAD>
__launch_bounds__(256)
__global__ void ptag64_k(const int* __restrict__ ptr, const int2* __restrict__ ep,
                         const ushort4* __restrict__ hin, ushort4* __restrict__ hout,
                         const float4* __restrict__ Wk4, const float4* __restrict__ W04,
                         float4* __restrict__ acc4, const float4* __restrict__ bias4,
                         const float* __restrict__ Wout, const float* __restrict__ bout,
                         float* __restrict__ outv, int n) {
  __shared__ float4 Wl[1024];  // 64x64 weight (reused for W0 in FIRST phase B)
  __shared__ float4 tl4[256];  // t tile, slot = ln*16 + (j4^ln)  (bank-clean)
  const float* tl = (const float*)tl4;
  int tid = threadIdx.x;
  for (int i = tid; i < 1024; i += 256) Wl[i] = Wk4[i];
  int gid = blockIdx.x * 256 + tid;
  int node = gid >> 4, j4 = gid & 15, ln = tid >> 4;

  float4 t = make_float4(0.f, 0.f, 0.f, 0.f);
  if (node < n) {
    t = gather<16>(ptr, ep, hin, node, j4);
    if (!LAST) hout[(size_t)node * 16 + j4] = pack_bf(t);
  }
  tl4[ln * 16 + (j4 ^ ln)] = t;
  __syncthreads();

  float4 a = make_float4(0.f, 0.f, 0.f, 0.f);
  if (!FIRST && node < n) a = acc4[(size_t)node * 16 + j4];
  mm_acc(tl, Wl, ln, j4, a);
  if (FIRST) {  // phase B: own-term h0 @ W0, same LDS buffers
    __syncthreads();
    for (int i = tid; i < 1024; i += 256) Wl[i] = W04[i];
    float4 own = make_float4(0.f, 0.f, 0.f, 0.f);
    if (node < n) {
      ushort4 h = hin[(size_t)node * 16 + j4];
      own = make_float4(bf2f(h.x), bf2f(h.y), bf2f(h.z), bf2f(h.w));
    }
    tl4[ln * 16 + (j4 ^ ln)] = own;
    __syncthreads();
    mm_acc(tl, Wl, ln, j4, a);
  }
  if (node >= n) return;  // no barriers below

  if (LAST) {
    float4 b = bias4[j4];
    a.x += b.x; a.y += b.y; a.z += b.z; a.w += b.w;
    a.x = (a.x >= 0.f) ? a.x : 0.01f * a.x;
    a.y = (a.y >= 0.f) ? a.y : 0.01f * a.y;
    a.z = (a.z >= 0.f) ? a.z : 0.01f * a.z;
    a.w = (a.w >= 0.f) ? a.w : 0.01f * a.w;
    if (HEAD) {
      float v = a.x * Wout[4 * j4] + a.y * Wout[4 * j4 + 1] +
                a.z * Wout[4 * j4 + 2] + a.w * Wout[4 * j4 + 3];
      v += __shfl_down(v, 8, 16);
      v += __shfl_down(v, 4, 16);
      v += __shfl_down(v, 2, 16);
      v += __shfl_down(v, 1, 16);
      if (j4 == 0) outv[node] = v + bout[0];
    } else {
      hout[(size_t)node * 16 + j4] = pack_bf(a);  // activated layer output
    }
  } else {
    acc4[(size_t)node * 16 + j4] = a;
  }
}

// ---------- fused prop + matmul, layer 1: F_in=16 (4 lanes/node, 64 nodes/block) ----------
template <bool FIRST, bool LAST>
__launch_bounds__(256)
__global__ void ptag16_k(const int* __restrict__ ptr, const int2* __restrict__ ep,
                         const ushort4* __restrict__ hin, ushort4* __restrict__ hout,
                         const float4* __restrict__ Wk4, const float4* __restrict__ W04,
                         float4* __restrict__ acc4, const float4* __restrict__ bias4,
                         ushort4* __restrict__ outbuf, int n) {
  __shared__ float4 Wl[256];               // 16x64 W_k
  __shared__ float4 W0l[FIRST ? 256 : 1];  // 16x64 W_0
  __shared__ float4 tl4[64 * 5];           // t tile, stride 5 float4
  const float* tl = (const float*)tl4;
  int tid = threadIdx.x;
  Wl[tid] = Wk4[tid];
  if (FIRST) W0l[tid] = W04[tid];
  int gid = blockIdx.x * 256 + tid;
  int node = gid >> 2, q = tid & 3, ln = tid >> 2;

  float4 t = make_float4(0.f, 0.f, 0.f, 0.f);
  if (node < n) {
    t = gather<4>(ptr, ep, hin, node, q);
    if (!LAST) hout[(size_t)node * 4 + q] = pack_bf(t);
  }
  tl4[ln * 5 + q] = t;
  __syncthreads();

  float4 a[4];
#pragma unroll
  for (int c = 0; c < 4; ++c) a[c] = make_float4(0.f, 0.f, 0.f, 0.f);
  if (!FIRST && node < n) {
#pragma unroll
    for (int c = 0; c < 4; ++c) a[c] = acc4[(size_t)node * 16 + 4 * q + c];
  }
#pragma unroll 4
  for (int i = 0; i < 16; ++i) {
    float tv = tl[ln * 20 + i];
#pragma unroll
    for (int c = 0; c < 4; ++c) {
      float4 wv = Wl[i * 16 + 4 * q + c];
      a[c].x = fmaf(tv, wv.x, a[c].x); a[c].y = fmaf(tv, wv.y, a[c].y);
      a[c].z = fmaf(tv, wv.z, a[c].z); a[c].w = fmaf(tv, wv.w, a[c].w);
    }
  }
  if (FIRST) {  // own-term x @ W0
    __syncthreads();
    float4 own = make_float4(0.f, 0.f, 0.f, 0.f);
    if (node < n) {
      ushort4 h = hin[(size_t)node * 4 + q];
      own = make_float4(bf2f(h.x), bf2f(h.y), bf2f(h.z), bf2f(h.w));
    }
    tl4[ln * 5 + q] = own;
    __syncthreads();
#pragma unroll 4
    for (int i = 0; i < 16; ++i) {
      float tv = tl[ln * 20 + i];
#pragma unroll
      for (int c = 0; c < 4; ++c) {
        float4 wv = W0l[i * 16 + 4 * q + c];
        a[c].x = fmaf(tv, wv.x, a[c].x); a[c].y = fmaf(tv, wv.y, a[c].y);
        a[c].z = fmaf(tv, wv.z, a[c].z); a[c].w = fmaf(tv, wv.w, a[c].w);
      }
    }
  }
  if (node >= n) return;

  if (LAST) {
#pragma unroll
    for (int c = 0; c < 4; ++c) {
      float4 b = bias4[4 * q + c];
      a[c].x += b.x; a[c].y += b.y; a[c].z += b.z; a[c].w += b.w;
      a[c].x = (a[c].x >= 0.f) ? a[c].x : 0.01f * a[c].x;
      a[c].y = (a[c].y >= 0.f) ? a[c].y : 0.01f * a[c].y;
      a[c].z = (a[c].z >= 0.f) ? a[c].z : 0.01f * a[c].z;
      a[c].w = (a[c].w >= 0.f) ? a[c].w : 0.01f * a[c].w;
      outbuf[(size_t)node * 16 + 4 * q + c] = pack_bf(a[c]);  // activated h1, bf16
    }
  } else {
#pragma unroll
    for (int c = 0; c < 4; ++c) acc4[(size_t)node * 16 + 4 * q + c] = a[c];
  }
}

extern "C" void kernel_launch(void* const* d_in, const int* in_sizes, int n_in,
                              void* d_out, int out_size, void* d_ws, size_t ws_size,
                              hipStream_t stream) {
  const float* x    = (const float*)d_in[0];
  const int*   ei   = (const int*)d_in[1];
  const float* ew   = (const float*)d_in[2];
  const float* W1   = (const float*)d_in[4];
  const float* b1   = (const float*)d_in[5];
  const float* W2   = (const float*)d_in[6];
  const float* b2   = (const float*)d_in[7];
  const float* Wout = (const float*)d_in[8];
  const float* bout = (const float*)d_in[9];
  float* out = (float*)d_out;

  const int N = in_sizes[0] / 16;
  const int E = in_sizes[2];
  const int* src = ei;
  const int* dst = ei + E;

  char* ws = (char*)d_ws;
  size_t off = 0;
  auto alloc = [&](size_t bytes) {
    char* p = ws + off;
    off = (off + bytes + 255) & ~(size_t)255;
    return p;
  };
  u64*     pack = (u64*)alloc((size_t)N * 8);
  float*   dinv = (float*)alloc((size_t)N * 4);
  int*     ptr  = (int*)alloc(((size_t)N + 1) * 4);
  int*     bsum = (int*)alloc(4096);
  int*     rank = (int*)alloc((size_t)E * 4);
  int2*    ep   = (int2*)alloc((size_t)E * 8);
  ushort4* xb   = (ushort4*)alloc((size_t)N * 16 * 2);       // N x 16 bf16
  ushort4* hb0  = (ushort4*)alloc((size_t)N * 64 * 2);       // t ping
  ushort4* hb1  = (ushort4*)alloc((size_t)N * 64 * 2);       // t pong
  ushort4* hb2  = (ushort4*)alloc((size_t)N * 64 * 2);       // layer outputs
  float4*  accf = (float4*)alloc((size_t)N * 64 * 4);        // fp32 acc

  hipMemsetAsync(pack, 0, (size_t)N * 8, stream);

  int gE = (E + 255) / 256;
  int gN = (N + 255) / 256;
  degcount_k<<<gE, 256, 0, stream>>>(dst, ew, pack, rank, E, (const float4*)x, xb, N * 4);
  scan_blocks<<<gN, 256, 0, stream>>>(pack, dinv, ptr, bsum, N);
  scan_sums<<<1, 512, 0, stream>>>(bsum, gN);
  scan_add<<<gN, 256, 0, stream>>>(ptr, bsum, N, E);
  fill_k<<<gE, 256, 0, stream>>>(src, dst, ew, dinv, ptr, rank, ep, E);

  int g4  = (N * 4 + 255) / 256;   // layer-1 fused (4 lanes/node)
  int g16 = (N * 16 + 255) / 256;  // F=64 fused (16 lanes/node)

  auto W1k = [&](int k) { return (const float4*)(W1 + (size_t)k * 1024); };
  auto W2k = [&](int l, int k) { return (const float4*)(W2 + ((size_t)l * 5 + k) * 4096); };

  // ---- Layer 1 (16 -> 64): acc in accf, t ping-pong hb0/hb1 (stride 4), h1 -> hb2 ----
  ptag16_k<true,  false><<<g4, 256, 0, stream>>>(ptr, ep, xb,  hb0, W1k(1), W1k(0), accf, nullptr, nullptr, N);
  ptag16_k<false, false><<<g4, 256, 0, stream>>>(ptr, ep, hb0, hb1, W1k(2), nullptr, accf, nullptr, nullptr, N);
  ptag16_k<false, false><<<g4, 256, 0, stream>>>(ptr, ep, hb1, hb0, W1k(3), nullptr, accf, nullptr, nullptr, N);
  ptag16_k<false, true ><<<g4, 256, 0, stream>>>(ptr, ep, hb0, nullptr, W1k(4), nullptr, accf,
                                                 (const float4*)b1, hb2, N);

  // ---- Layer 2 (64 -> 64): input hb2, t ping-pong hb0/hb1, h2 -> hb2 ----
  ptag64_k<true,  false, false><<<g16, 256, 0, stream>>>(ptr, ep, hb2, hb0, W2k(0,1), W2k(0,0), accf,
                                                         nullptr, nullptr, nullptr, nullptr, N);
  ptag64_k<false, false, false><<<g16, 256, 0, stream>>>(ptr, ep, hb0, hb1, W2k(0,2), nullptr, accf,
                                                         nullptr, nullptr, nullptr, nullptr, N);
  ptag64_k<false, false, false><<<g16, 256, 0, stream>>>(ptr, ep, hb1, hb0, W2k(0,3), nullptr, accf,
                                                         nullptr, nullptr, nullptr, nullptr, N);
  ptag64_k<false, true,  false><<<g16, 256, 0, stream>>>(ptr, ep, hb0, hb2, W2k(0,4), nullptr, accf,
                                                         (const float4*)b2, nullptr, nullptr, nullptr, N);

  // ---- Layer 3 (64 -> 64) + head: input hb2, head -> out ----
  ptag64_k<true,  false, false><<<g16, 256, 0, stream>>>(ptr, ep, hb2, hb0, W2k(1,1), W2k(1,0), accf,
                                                         nullptr, nullptr, nullptr, nullptr, N);
  ptag64_k<false, false, false><<<g16, 256, 0, stream>>>(ptr, ep, hb0, hb1, W2k(1,2), nullptr, accf,
                                                         nullptr, nullptr, nullptr, nullptr, N);
  ptag64_k<false, false, false><<<g16, 256, 0, stream>>>(ptr, ep, hb1, hb0, W2k(1,3), nullptr, accf,
                                                         nullptr, nullptr, nullptr, nullptr, N);
  ptag64_k<false, true,  true ><<<g16, 256, 0, stream>>>(ptr, ep, hb0, nullptr, W2k(1,4), nullptr, accf,
                                                         (const float4*)(b2 + 64), Wout, bout, out, N);
}

// Round 9
// 1196.646 us; speedup vs baseline: 1.0463x; 1.0463x over previous
//
#include <hip/hip_runtime.h>

// ---------------------------------------------------------------------------
// TAGCN node regression: 3 TAGConv layers (K=4) + linear head, fp32 math.
// CSR-by-dst built once per launch (rank from the degree atomic; fill has no
// atomics). Propagation fused with matmul accumulation; F=64 kernel: 20480 B
// LDS (8 blocks/CU), 28-VGPR scalar-broadcast mm loop.
// R9: R7's proven 2-edge gather (R8's 4-edge+nt regressed); ALL inter-dispatch
// tensors (x, t, h, acc) in FP16 e5m10 — acc traffic halves vs fp32, and
// h/t gain 8x mantissa vs bf16 to pay for the fp16 acc round-trips.
// Atomic floor ~0.73 TB/s write-through -> degcount ~150us is structural.
// ---------------------------------------------------------------------------

typedef unsigned long long u64;

__device__ __forceinline__ float h2f(unsigned short u) {
  _Float16 h;
  __builtin_memcpy(&h, &u, 2);
  return (float)h;
}
__device__ __forceinline__ unsigned short f2h(float f) {
  _Float16 h = (_Float16)f;  // RNE
  unsigned short u;
  __builtin_memcpy(&u, &h, 2);
  return u;
}
__device__ __forceinline__ ushort4 pack_h(float4 v) {
  ushort4 r;
  r.x = f2h(v.x); r.y = f2h(v.y); r.z = f2h(v.z); r.w = f2h(v.w);
  return r;
}
__device__ __forceinline__ float4 unpack_h(ushort4 u) {
  return make_float4(h2f(u.x), h2f(u.y), h2f(u.z), h2f(u.w));
}

// one 64-bit atomic per edge: [count:16 | sum_w Q16.32 fixed point:48]
// + fused x->fp16 convert (independent work, saves a dispatch)
__global__ void degcount_k(const int* __restrict__ dst, const float* __restrict__ w,
                           u64* __restrict__ pack, int* __restrict__ rank, int E,
                           const float4* __restrict__ x4, ushort4* __restrict__ xh, int n4) {
  int e = blockIdx.x * blockDim.x + threadIdx.x;
  if (e < n4) xh[e] = pack_h(x4[e]);
  if (e >= E) return;
  int d = dst[e];
  u64 v = ((u64)1 << 48) | (u64)((double)w[e] * 4294967296.0);
  u64 old = atomicAdd(&pack[d], v);
  rank[e] = (int)(old >> 48);
}

// scan (256/block) fused with degree decode -> dinv
__global__ void scan_blocks(const u64* __restrict__ pack, float* __restrict__ dinv,
                            int* __restrict__ ptr, int* __restrict__ bsum, int n) {
  __shared__ int s[256];
  int tid = threadIdx.x;
  int i = blockIdx.x * 256 + tid;
  int v = 0;
  if (i < n) {
    u64 p = pack[i];
    v = (int)(p >> 48);
    float d = (float)((double)(p & 0xFFFFFFFFFFFFULL) * (1.0 / 4294967296.0));
    dinv[i] = (d > 0.f) ? rsqrtf(fmaxf(d, 1e-30f)) : 0.f;
  }
  s[tid] = v;
  __syncthreads();
#pragma unroll
  for (int off = 1; off < 256; off <<= 1) {
    int t = (tid >= off) ? s[tid - off] : 0;
    __syncthreads();
    s[tid] += t;
    __syncthreads();
  }
  if (i < n) ptr[i] = s[tid] - v;
  if (tid == 255) bsum[blockIdx.x] = s[255];
}

__global__ void scan_sums(int* __restrict__ bsum, int nb) {
  __shared__ int s[512];
  int tid = threadIdx.x;
  int v = (tid < nb) ? bsum[tid] : 0;
  s[tid] = v;
  __syncthreads();
#pragma unroll
  for (int off = 1; off < 512; off <<= 1) {
    int t = (tid >= off) ? s[tid - off] : 0;
    __syncthreads();
    s[tid] += t;
    __syncthreads();
  }
  if (tid < nb) bsum[tid] = s[tid] - v;
}

__global__ void scan_add(int* __restrict__ ptr, const int* __restrict__ bsum, int n, int E) {
  int i = blockIdx.x * blockDim.x + threadIdx.x;
  if (i < n) ptr[i] += bsum[i >> 8];
  if (i == 0) ptr[n] = E;
}

// scatter edges into CSR slots (atomic-free); payload = {src, folded norm}
__global__ void fill_k(const int* __restrict__ src, const int* __restrict__ dst,
                       const float* __restrict__ w, const float* __restrict__ dinv,
                       const int* __restrict__ ptr, const int* __restrict__ rank,
                       int2* __restrict__ ep, int E) {
  int e = blockIdx.x * blockDim.x + threadIdx.x;
  if (e >= E) return;
  int s = src[e], d = dst[e];
  float nv = dinv[s] * w[e] * dinv[d];
  int pos = ptr[d] + rank[e];
  ep[pos] = make_int2(s, __float_as_int(nv));
}

// gather t[f4] = sum_e w_e * fp16(hin[src_e][f4]); R7's 2-edge unroll
template <int F4>
__device__ __forceinline__ float4 gather(const int* __restrict__ ptr, const int2* __restrict__ ep,
                                         const ushort4* __restrict__ hin, int node, int f4) {
  int e0 = ptr[node], e1 = ptr[node + 1];
  float4 a = make_float4(0.f, 0.f, 0.f, 0.f);
  int e = e0;
  if ((e & 1) && e < e1) {
    int2 p = ep[e];
    float w0 = __int_as_float(p.y);
    ushort4 h = hin[(size_t)p.x * F4 + f4];
    a.x = fmaf(w0, h2f(h.x), a.x); a.y = fmaf(w0, h2f(h.y), a.y);
    a.z = fmaf(w0, h2f(h.z), a.z); a.w = fmaf(w0, h2f(h.w), a.w);
    ++e;
  }
  for (; e + 1 < e1; e += 2) {
    int4 p = *(const int4*)(ep + e);  // 2 edges, 16B aligned
    float w0 = __int_as_float(p.y), w1 = __int_as_float(p.w);
    ushort4 h0 = hin[(size_t)p.x * F4 + f4];
    ushort4 h1 = hin[(size_t)p.z * F4 + f4];
    a.x = fmaf(w0, h2f(h0.x), a.x); a.y = fmaf(w0, h2f(h0.y), a.y);
    a.z = fmaf(w0, h2f(h0.z), a.z); a.w = fmaf(w0, h2f(h0.w), a.w);
    a.x = fmaf(w1, h2f(h1.x), a.x); a.y = fmaf(w1, h2f(h1.y), a.y);
    a.z = fmaf(w1, h2f(h1.z), a.z); a.w = fmaf(w1, h2f(h1.w), a.w);
  }
  if (e < e1) {
    int2 p = ep[e];
    float w0 = __int_as_float(p.y);
    ushort4 h = hin[(size_t)p.x * F4 + f4];
    a.x = fmaf(w0, h2f(h.x), a.x); a.y = fmaf(w0, h2f(h.y), a.y);
    a.z = fmaf(w0, h2f(h.z), a.z); a.w = fmaf(w0, h2f(h.w), a.w);
  }
  return a;
}

// scalar-broadcast mm accumulate: a += t(group ln) @ W  (28-VGPR shape, R6).
// t element i of group ln lives at word ln*64 + (((i>>2)^ln)<<2 | (i&3)).
__device__ __forceinline__ void mm_acc(const float* __restrict__ tl, const float4* __restrict__ Wl,
                                       int ln, int j4, float4& a) {
#pragma unroll 8
  for (int i = 0; i < 64; ++i) {
    float tv = tl[ln * 64 + ((((i >> 2) ^ ln) << 2) | (i & 3))];
    float4 wv = Wl[i * 16 + j4];
    a.x = fmaf(tv, wv.x, a.x); a.y = fmaf(tv, wv.y, a.y);
    a.z = fmaf(tv, wv.z, a.z); a.w = fmaf(tv, wv.w, a.w);
  }
}

// ---------- fused prop + matmul, F=64 (16 lanes/node, 16 nodes/block) ----------
// LDS = 16K W + 4K XOR-swizzled t tile = 20480 B -> 8 blocks/CU (VGPR ~28-40).
template <bool FIRST, bool LAST, bool HEAD>
__launch_bounds__(256)
__global__ void ptag64_k(const int* __restrict__ ptr, const int2* __restrict__ ep,
                         const ushort4* __restrict__ hin, ushort4* __restrict__ hout,
                         const float4* __restrict__ Wk4, const float4* __restrict__ W04,
                         ushort4* __restrict__ acch, const float4* __restrict__ bias4,
                         const float* __restrict__ Wout, const float* __restrict__ bout,
                         float* __restrict__ outv, int n) {
  __shared__ float4 Wl[1024];  // 64x64 weight (reused for W0 in FIRST phase B)
  __shared__ float4 tl4[256];  // t tile, slot = ln*16 + (j4^ln)  (bank-clean)
  const float* tl = (const float*)tl4;
  int tid = threadIdx.x;
  for (int i = tid; i < 1024; i += 256) Wl[i] = Wk4[i];
  int gid = blockIdx.x * 256 + tid;
  int node = gid >> 4, j4 = gid & 15, ln = tid >> 4;

  float4 t = make_float4(0.f, 0.f, 0.f, 0.f);
  if (node < n) {
    t = gather<16>(ptr, ep, hin, node, j4);
    if (!LAST) hout[(size_t)node * 16 + j4] = pack_h(t);
  }
  tl4[ln * 16 + (j4 ^ ln)] = t;
  __syncthreads();

  float4 a = make_float4(0.f, 0.f, 0.f, 0.f);
  if (!FIRST && node < n) a = unpack_h(acch[(size_t)node * 16 + j4]);
  mm_acc(tl, Wl, ln, j4, a);
  if (FIRST) {  // phase B: own-term h0 @ W0, same LDS buffers
    __syncthreads();
    for (int i = tid; i < 1024; i += 256) Wl[i] = W04[i];
    float4 own = make_float4(0.f, 0.f, 0.f, 0.f);
    if (node < n) own = unpack_h(hin[(size_t)node * 16 + j4]);
    tl4[ln * 16 + (j4 ^ ln)] = own;
    __syncthreads();
    mm_acc(tl, Wl, ln, j4, a);
  }
  if (node >= n) return;  // no barriers below

  if (LAST) {
    float4 b = bias4[j4];
    a.x += b.x; a.y += b.y; a.z += b.z; a.w += b.w;
    a.x = (a.x >= 0.f) ? a.x : 0.01f * a.x;
    a.y = (a.y >= 0.f) ? a.y : 0.01f * a.y;
    a.z = (a.z >= 0.f) ? a.z : 0.01f * a.z;
    a.w = (a.w >= 0.f) ? a.w : 0.01f * a.w;
    if (HEAD) {
      float v = a.x * Wout[4 * j4] + a.y * Wout[4 * j4 + 1] +
                a.z * Wout[4 * j4 + 2] + a.w * Wout[4 * j4 + 3];
      v += __shfl_down(v, 8, 16);
      v += __shfl_down(v, 4, 16);
      v += __shfl_down(v, 2, 16);
      v += __shfl_down(v, 1, 16);
      if (j4 == 0) outv[node] = v + bout[0];
    } else {
      hout[(size_t)node * 16 + j4] = pack_h(a);  // activated layer output
    }
  } else {
    acch[(size_t)node * 16 + j4] = pack_h(a);
  }
}

// ---------- fused prop + matmul, layer 1: F_in=16 (4 lanes/node, 64 nodes/block) ----------
template <bool FIRST, bool LAST>
__launch_bounds__(256)
__global__ void ptag16_k(const int* __restrict__ ptr, const int2* __restrict__ ep,
                         const ushort4* __restrict__ hin, ushort4* __restrict__ hout,
                         const float4* __restrict__ Wk4, const float4* __restrict__ W04,
                         ushort4* __restrict__ acch, const float4* __restrict__ bias4,
                         ushort4* __restrict__ outbuf, int n) {
  __shared__ float4 Wl[256];               // 16x64 W_k
  __shared__ float4 W0l[FIRST ? 256 : 1];  // 16x64 W_0
  __shared__ float4 tl4[64 * 5];           // t tile, stride 5 float4
  const float* tl = (const float*)tl4;
  int tid = threadIdx.x;
  Wl[tid] = Wk4[tid];
  if (FIRST) W0l[tid] = W04[tid];
  int gid = blockIdx.x * 256 + tid;
  int node = gid >> 2, q = tid & 3, ln = tid >> 2;

  float4 t = make_float4(0.f, 0.f, 0.f, 0.f);
  if (node < n) {
    t = gather<4>(ptr, ep, hin, node, q);
    if (!LAST) hout[(size_t)node * 4 + q] = pack_h(t);
  }
  tl4[ln * 5 + q] = t;
  __syncthreads();

  float4 a[4];
#pragma unroll
  for (int c = 0; c < 4; ++c) a[c] = make_float4(0.f, 0.f, 0.f, 0.f);
  if (!FIRST && node < n) {
#pragma unroll
    for (int c = 0; c < 4; ++c) a[c] = unpack_h(acch[(size_t)node * 16 + 4 * q + c]);
  }
#pragma unroll 4
  for (int i = 0; i < 16; ++i) {
    float tv = tl[ln * 20 + i];
#pragma unroll
    for (int c = 0; c < 4; ++c) {
      float4 wv = Wl[i * 16 + 4 * q + c];
      a[c].x = fmaf(tv, wv.x, a[c].x); a[c].y = fmaf(tv, wv.y, a[c].y);
      a[c].z = fmaf(tv, wv.z, a[c].z); a[c].w = fmaf(tv, wv.w, a[c].w);
    }
  }
  if (FIRST) {  // own-term x @ W0
    __syncthreads();
    float4 own = make_float4(0.f, 0.f, 0.f, 0.f);
    if (node < n) own = unpack_h(hin[(size_t)node * 4 + q]);
    tl4[ln * 5 + q] = own;
    __syncthreads();
#pragma unroll 4
    for (int i = 0; i < 16; ++i) {
      float tv = tl[ln * 20 + i];
#pragma unroll
      for (int c = 0; c < 4; ++c) {
        float4 wv = W0l[i * 16 + 4 * q + c];
        a[c].x = fmaf(tv, wv.x, a[c].x); a[c].y = fmaf(tv, wv.y, a[c].y);
        a[c].z = fmaf(tv, wv.z, a[c].z); a[c].w = fmaf(tv, wv.w, a[c].w);
      }
    }
  }
  if (node >= n) return;

  if (LAST) {
#pragma unroll
    for (int c = 0; c < 4; ++c) {
      float4 b = bias4[4 * q + c];
      a[c].x += b.x; a[c].y += b.y; a[c].z += b.z; a[c].w += b.w;
      a[c].x = (a[c].x >= 0.f) ? a[c].x : 0.01f * a[c].x;
      a[c].y = (a[c].y >= 0.f) ? a[c].y : 0.01f * a[c].y;
      a[c].z = (a[c].z >= 0.f) ? a[c].z : 0.01f * a[c].z;
      a[c].w = (a[c].w >= 0.f) ? a[c].w : 0.01f * a[c].w;
      outbuf[(size_t)node * 16 + 4 * q + c] = pack_h(a[c]);  // activated h1, fp16
    }
  } else {
#pragma unroll
    for (int c = 0; c < 4; ++c) acch[(size_t)node * 16 + 4 * q + c] = pack_h(a[c]);
  }
}

extern "C" void kernel_launch(void* const* d_in, const int* in_sizes, int n_in,
                              void* d_out, int out_size, void* d_ws, size_t ws_size,
                              hipStream_t stream) {
  const float* x    = (const float*)d_in[0];
  const int*   ei   = (const int*)d_in[1];
  const float* ew   = (const float*)d_in[2];
  const float* W1   = (const float*)d_in[4];
  const float* b1   = (const float*)d_in[5];
  const float* W2   = (const float*)d_in[6];
  const float* b2   = (const float*)d_in[7];
  const float* Wout = (const float*)d_in[8];
  const float* bout = (const float*)d_in[9];
  float* out = (float*)d_out;

  const int N = in_sizes[0] / 16;
  const int E = in_sizes[2];
  const int* src = ei;
  const int* dst = ei + E;

  char* ws = (char*)d_ws;
  size_t off = 0;
  auto alloc = [&](size_t bytes) {
    char* p = ws + off;
    off = (off + bytes + 255) & ~(size_t)255;
    return p;
  };
  u64*     pack = (u64*)alloc((size_t)N * 8);
  float*   dinv = (float*)alloc((size_t)N * 4);
  int*     ptr  = (int*)alloc(((size_t)N + 1) * 4);
  int*     bsum = (int*)alloc(4096);
  int*     rank = (int*)alloc((size_t)E * 4);
  int2*    ep   = (int2*)alloc((size_t)E * 8);
  ushort4* xh   = (ushort4*)alloc((size_t)N * 16 * 2);       // N x 16 fp16
  ushort4* hb0  = (ushort4*)alloc((size_t)N * 64 * 2);       // t ping
  ushort4* hb1  = (ushort4*)alloc((size_t)N * 64 * 2);       // t pong
  ushort4* hb2  = (ushort4*)alloc((size_t)N * 64 * 2);       // layer outputs
  ushort4* acch = (ushort4*)alloc((size_t)N * 64 * 2);       // fp16 acc

  hipMemsetAsync(pack, 0, (size_t)N * 8, stream);

  int gE = (E + 255) / 256;
  int gN = (N + 255) / 256;
  degcount_k<<<gE, 256, 0, stream>>>(dst, ew, pack, rank, E, (const float4*)x, xh, N * 4);
  scan_blocks<<<gN, 256, 0, stream>>>(pack, dinv, ptr, bsum, N);
  scan_sums<<<1, 512, 0, stream>>>(bsum, gN);
  scan_add<<<gN, 256, 0, stream>>>(ptr, bsum, N, E);
  fill_k<<<gE, 256, 0, stream>>>(src, dst, ew, dinv, ptr, rank, ep, E);

  int g4  = (N * 4 + 255) / 256;   // layer-1 fused (4 lanes/node)
  int g16 = (N * 16 + 255) / 256;  // F=64 fused (16 lanes/node)

  auto W1k = [&](int k) { return (const float4*)(W1 + (size_t)k * 1024); };
  auto W2k = [&](int l, int k) { return (const float4*)(W2 + ((size_t)l * 5 + k) * 4096); };

  // ---- Layer 1 (16 -> 64): acc in acch, t ping-pong hb0/hb1 (stride 4), h1 -> hb2 ----
  ptag16_k<true,  false><<<g4, 256, 0, stream>>>(ptr, ep, xh,  hb0, W1k(1), W1k(0), acch, nullptr, nullptr, N);
  ptag16_k<false, false><<<g4, 256, 0, stream>>>(ptr, ep, hb0, hb1, W1k(2), nullptr, acch, nullptr, nullptr, N);
  ptag16_k<false, false><<<g4, 256, 0, stream>>>(ptr, ep, hb1, hb0, W1k(3), nullptr, acch, nullptr, nullptr, N);
  ptag16_k<false, true ><<<g4, 256, 0, stream>>>(ptr, ep, hb0, nullptr, W1k(4), nullptr, acch,
                                                 (const float4*)b1, hb2, N);

  // ---- Layer 2 (64 -> 64): input hb2, t ping-pong hb0/hb1, h2 -> hb2 ----
  ptag64_k<true,  false, false><<<g16, 256, 0, stream>>>(ptr, ep, hb2, hb0, W2k(0,1), W2k(0,0), acch,
                                                         nullptr, nullptr, nullptr, nullptr, N);
  ptag64_k<false, false, false><<<g16, 256, 0, stream>>>(ptr, ep, hb0, hb1, W2k(0,2), nullptr, acch,
                                                         nullptr, nullptr, nullptr, nullptr, N);
  ptag64_k<false, false, false><<<g16, 256, 0, stream>>>(ptr, ep, hb1, hb0, W2k(0,3), nullptr, acch,
                                                         nullptr, nullptr, nullptr, nullptr, N);
  ptag64_k<false, true,  false><<<g16, 256, 0, stream>>>(ptr, ep, hb0, hb2, W2k(0,4), nullptr, acch,
                                                         (const float4*)b2, nullptr, nullptr, nullptr, N);

  // ---- Layer 3 (64 -> 64) + head: input hb2, head -> out ----
  ptag64_k<true,  false, false><<<g16, 256, 0, stream>>>(ptr, ep, hb2, hb0, W2k(1,1), W2k(1,0), acch,
                                                         nullptr, nullptr, nullptr, nullptr, N);
  ptag64_k<false, false, false><<<g16, 256, 0, stream>>>(ptr, ep, hb0, hb1, W2k(1,2), nullptr, acch,
                                                         nullptr, nullptr, nullptr, nullptr, N);
  ptag64_k<false, false, false><<<g16, 256, 0, stream>>>(ptr, ep, hb1, hb0, W2k(1,3), nullptr, acch,
                                                         nullptr, nullptr, nullptr, nullptr, N);
  ptag64_k<false, true,  true ><<<g16, 256, 0, stream>>>(ptr, ep, hb0, nullptr, W2k(1,4), nullptr, acch,
                                                         (const float4*)(b2 + 64), Wout, bout, out, N);
}

// Round 10
// 1178.642 us; speedup vs baseline: 1.0623x; 1.0153x over previous
//
#include <hip/hip_runtime.h>

// ---------------------------------------------------------------------------
// TAGCN node regression: 3 TAGConv layers (K=4) + linear head, fp32 math.
// CSR-by-dst built once per launch (rank from the degree atomic; fill has no
// atomics). Propagation fused with matmul accumulation; F=64 kernel: 20480 B
// LDS (8 blocks/CU), 28-VGPR scalar-broadcast mm loop. All inter-dispatch
// tensors fp16 (R9). R10: edge payload packed to 4 B/edge —
// [norm fp16 sans sign :15 | src :17] (N<2^17, norm>=0) — halves the ep
// stream in all 12 props and halves fill's scattered writes.
// Atomic floor ~0.73 TB/s write-through -> degcount ~160us is structural.
// ---------------------------------------------------------------------------

typedef unsigned long long u64;
typedef unsigned int u32;

__device__ __forceinline__ float h2f(unsigned short u) {
  _Float16 h;
  __builtin_memcpy(&h, &u, 2);
  return (float)h;
}
__device__ __forceinline__ unsigned short f2h(float f) {
  _Float16 h = (_Float16)f;  // RNE
  unsigned short u;
  __builtin_memcpy(&u, &h, 2);
  return u;
}
__device__ __forceinline__ ushort4 pack_h(float4 v) {
  ushort4 r;
  r.x = f2h(v.x); r.y = f2h(v.y); r.z = f2h(v.z); r.w = f2h(v.w);
  return r;
}
__device__ __forceinline__ float4 unpack_h(ushort4 u) {
  return make_float4(h2f(u.x), h2f(u.y), h2f(u.z), h2f(u.w));
}
// packed edge: [norm15 | src17]
__device__ __forceinline__ void dec_ep(u32 u, int& s, float& w) {
  s = (int)(u & 0x1FFFFu);
  w = h2f((unsigned short)(u >> 17));
}

// one 64-bit atomic per edge: [count:16 | sum_w Q16.32 fixed point:48]
// + fused x->fp16 convert (independent work, saves a dispatch)
__global__ void degcount_k(const int* __restrict__ dst, const float* __restrict__ w,
                           u64* __restrict__ pack, int* __restrict__ rank, int E,
                           const float4* __restrict__ x4, ushort4* __restrict__ xh, int n4) {
  int e = blockIdx.x * blockDim.x + threadIdx.x;
  if (e < n4) xh[e] = pack_h(x4[e]);
  if (e >= E) return;
  int d = dst[e];
  u64 v = ((u64)1 << 48) | (u64)((double)w[e] * 4294967296.0);
  u64 old = atomicAdd(&pack[d], v);
  rank[e] = (int)(old >> 48);
}

// scan (256/block) fused with degree decode -> dinv
__global__ void scan_blocks(const u64* __restrict__ pack, float* __restrict__ dinv,
                            int* __restrict__ ptr, int* __restrict__ bsum, int n) {
  __shared__ int s[256];
  int tid = threadIdx.x;
  int i = blockIdx.x * 256 + tid;
  int v = 0;
  if (i < n) {
    u64 p = pack[i];
    v = (int)(p >> 48);
    float d = (float)((double)(p & 0xFFFFFFFFFFFFULL) * (1.0 / 4294967296.0));
    dinv[i] = (d > 0.f) ? rsqrtf(fmaxf(d, 1e-30f)) : 0.f;
  }
  s[tid] = v;
  __syncthreads();
#pragma unroll
  for (int off = 1; off < 256; off <<= 1) {
    int t = (tid >= off) ? s[tid - off] : 0;
    __syncthreads();
    s[tid] += t;
    __syncthreads();
  }
  if (i < n) ptr[i] = s[tid] - v;
  if (tid == 255) bsum[blockIdx.x] = s[255];
}

__global__ void scan_sums(int* __restrict__ bsum, int nb) {
  __shared__ int s[512];
  int tid = threadIdx.x;
  int v = (tid < nb) ? bsum[tid] : 0;
  s[tid] = v;
  __syncthreads();
#pragma unroll
  for (int off = 1; off < 512; off <<= 1) {
    int t = (tid >= off) ? s[tid - off] : 0;
    __syncthreads();
    s[tid] += t;
    __syncthreads();
  }
  if (tid < nb) bsum[tid] = s[tid] - v;
}

__global__ void scan_add(int* __restrict__ ptr, const int* __restrict__ bsum, int n, int E) {
  int i = blockIdx.x * blockDim.x + threadIdx.x;
  if (i < n) ptr[i] += bsum[i >> 8];
  if (i == 0) ptr[n] = E;
}

// scatter edges into CSR slots (atomic-free); payload = [norm15|src17] u32
__global__ void fill_k(const int* __restrict__ src, const int* __restrict__ dst,
                       const float* __restrict__ w, const float* __restrict__ dinv,
                       const int* __restrict__ ptr, const int* __restrict__ rank,
                       u32* __restrict__ ep, int E) {
  int e = blockIdx.x * blockDim.x + threadIdx.x;
  if (e >= E) return;
  int s = src[e], d = dst[e];
  float nv = dinv[s] * w[e] * dinv[d];
  int pos = ptr[d] + rank[e];
  ep[pos] = ((u32)f2h(nv) << 17) | (u32)s;  // norm>=0 -> sign bit free
}

// gather t[f4] = sum_e w_e * fp16(hin[src_e][f4]); 2-edge unroll, 4B edges
template <int F4>
__device__ __forceinline__ float4 gather(const int* __restrict__ ptr, const u32* __restrict__ ep,
                                         const ushort4* __restrict__ hin, int node, int f4) {
  int e0 = ptr[node], e1 = ptr[node + 1];
  float4 a = make_float4(0.f, 0.f, 0.f, 0.f);
  int e = e0;
  if ((e & 1) && e < e1) {
    int s0; float w0; dec_ep(ep[e], s0, w0);
    ushort4 h = hin[(size_t)s0 * F4 + f4];
    a.x = fmaf(w0, h2f(h.x), a.x); a.y = fmaf(w0, h2f(h.y), a.y);
    a.z = fmaf(w0, h2f(h.z), a.z); a.w = fmaf(w0, h2f(h.w), a.w);
    ++e;
  }
  for (; e + 1 < e1; e += 2) {
    uint2 p = *(const uint2*)(ep + e);  // 2 edges, 8B aligned
    int s0, s1; float w0, w1;
    dec_ep(p.x, s0, w0);
    dec_ep(p.y, s1, w1);
    ushort4 h0 = hin[(size_t)s0 * F4 + f4];
    ushort4 h1 = hin[(size_t)s1 * F4 + f4];
    a.x = fmaf(w0, h2f(h0.x), a.x); a.y = fmaf(w0, h2f(h0.y), a.y);
    a.z = fmaf(w0, h2f(h0.z), a.z); a.w = fmaf(w0, h2f(h0.w), a.w);
    a.x = fmaf(w1, h2f(h1.x), a.x); a.y = fmaf(w1, h2f(h1.y), a.y);
    a.z = fmaf(w1, h2f(h1.z), a.z); a.w = fmaf(w1, h2f(h1.w), a.w);
  }
  if (e < e1) {
    int s0; float w0; dec_ep(ep[e], s0, w0);
    ushort4 h = hin[(size_t)s0 * F4 + f4];
    a.x = fmaf(w0, h2f(h.x), a.x); a.y = fmaf(w0, h2f(h.y), a.y);
    a.z = fmaf(w0, h2f(h.z), a.z); a.w = fmaf(w0, h2f(h.w), a.w);
  }
  return a;
}

// scalar-broadcast mm accumulate: a += t(group ln) @ W  (28-VGPR shape, R6).
// t element i of group ln lives at word ln*64 + (((i>>2)^ln)<<2 | (i&3)).
__device__ __forceinline__ void mm_acc(const float* __restrict__ tl, const float4* __restrict__ Wl,
                                       int ln, int j4, float4& a) {
#pragma unroll 8
  for (int i = 0; i < 64; ++i) {
    float tv = tl[ln * 64 + ((((i >> 2) ^ ln) << 2) | (i & 3))];
    float4 wv = Wl[i * 16 + j4];
    a.x = fmaf(tv, wv.x, a.x); a.y = fmaf(tv, wv.y, a.y);
    a.z = fmaf(tv, wv.z, a.z); a.w = fmaf(tv, wv.w, a.w);
  }
}

// ---------- fused prop + matmul, F=64 (16 lanes/node, 16 nodes/block) ----------
// LDS = 16K W + 4K XOR-swizzled t tile = 20480 B -> 8 blocks/CU (VGPR ~28-40).
template <bool FIRST, bool LAST, bool HEAD>
__launch_bounds__(256)
__global__ void ptag64_k(const int* __restrict__ ptr, const u32* __restrict__ ep,
                         const ushort4* __restrict__ hin, ushort4* __restrict__ hout,
                         const float4* __restrict__ Wk4, const float4* __restrict__ W04,
                         ushort4* __restrict__ acch, const float4* __restrict__ bias4,
                         const float* __restrict__ Wout, const float* __restrict__ bout,
                         float* __restrict__ outv, int n) {
  __shared__ float4 Wl[1024];  // 64x64 weight (reused for W0 in FIRST phase B)
  __shared__ float4 tl4[256];  // t tile, slot = ln*16 + (j4^ln)  (bank-clean)
  const float* tl = (const float*)tl4;
  int tid = threadIdx.x;
  for (int i = tid; i < 1024; i += 256) Wl[i] = Wk4[i];
  int gid = blockIdx.x * 256 + tid;
  int node = gid >> 4, j4 = gid & 15, ln = tid >> 4;

  float4 t = make_float4(0.f, 0.f, 0.f, 0.f);
  if (node < n) {
    t = gather<16>(ptr, ep, hin, node, j4);
    if (!LAST) hout[(size_t)node * 16 + j4] = pack_h(t);
  }
  tl4[ln * 16 + (j4 ^ ln)] = t;
  __syncthreads();

  float4 a = make_float4(0.f, 0.f, 0.f, 0.f);
  if (!FIRST && node < n) a = unpack_h(acch[(size_t)node * 16 + j4]);
  mm_acc(tl, Wl, ln, j4, a);
  if (FIRST) {  // phase B: own-term h0 @ W0, same LDS buffers
    __syncthreads();
    for (int i = tid; i < 1024; i += 256) Wl[i] = W04[i];
    float4 own = make_float4(0.f, 0.f, 0.f, 0.f);
    if (node < n) own = unpack_h(hin[(size_t)node * 16 + j4]);
    tl4[ln * 16 + (j4 ^ ln)] = own;
    __syncthreads();
    mm_acc(tl, Wl, ln, j4, a);
  }
  if (node >= n) return;  // no barriers below

  if (LAST) {
    float4 b = bias4[j4];
    a.x += b.x; a.y += b.y; a.z += b.z; a.w += b.w;
    a.x = (a.x >= 0.f) ? a.x : 0.01f * a.x;
    a.y = (a.y >= 0.f) ? a.y : 0.01f * a.y;
    a.z = (a.z >= 0.f) ? a.z : 0.01f * a.z;
    a.w = (a.w >= 0.f) ? a.w : 0.01f * a.w;
    if (HEAD) {
      float v = a.x * Wout[4 * j4] + a.y * Wout[4 * j4 + 1] +
                a.z * Wout[4 * j4 + 2] + a.w * Wout[4 * j4 + 3];
      v += __shfl_down(v, 8, 16);
      v += __shfl_down(v, 4, 16);
      v += __shfl_down(v, 2, 16);
      v += __shfl_down(v, 1, 16);
      if (j4 == 0) outv[node] = v + bout[0];
    } else {
      hout[(size_t)node * 16 + j4] = pack_h(a);  // activated layer output
    }
  } else {
    acch[(size_t)node * 16 + j4] = pack_h(a);
  }
}

// ---------- fused prop + matmul, layer 1: F_in=16 (4 lanes/node, 64 nodes/block) ----------
template <bool FIRST, bool LAST>
__launch_bounds__(256)
__global__ void ptag16_k(const int* __restrict__ ptr, const u32* __restrict__ ep,
                         const ushort4* __restrict__ hin, ushort4* __restrict__ hout,
                         const float4* __restrict__ Wk4, const float4* __restrict__ W04,
                         ushort4* __restrict__ acch, const float4* __restrict__ bias4,
                         ushort4* __restrict__ outbuf, int n) {
  __shared__ float4 Wl[256];               // 16x64 W_k
  __shared__ float4 W0l[FIRST ? 256 : 1];  // 16x64 W_0
  __shared__ float4 tl4[64 * 5];           // t tile, stride 5 float4
  const float* tl = (const float*)tl4;
  int tid = threadIdx.x;
  Wl[tid] = Wk4[tid];
  if (FIRST) W0l[tid] = W04[tid];
  int gid = blockIdx.x * 256 + tid;
  int node = gid >> 2, q = tid & 3, ln = tid >> 2;

  float4 t = make_float4(0.f, 0.f, 0.f, 0.f);
  if (node < n) {
    t = gather<4>(ptr, ep, hin, node, q);
    if (!LAST) hout[(size_t)node * 4 + q] = pack_h(t);
  }
  tl4[ln * 5 + q] = t;
  __syncthreads();

  float4 a[4];
#pragma unroll
  for (int c = 0; c < 4; ++c) a[c] = make_float4(0.f, 0.f, 0.f, 0.f);
  if (!FIRST && node < n) {
#pragma unroll
    for (int c = 0; c < 4; ++c) a[c] = unpack_h(acch[(size_t)node * 16 + 4 * q + c]);
  }
#pragma unroll 4
  for (int i = 0; i < 16; ++i) {
    float tv = tl[ln * 20 + i];
#pragma unroll
    for (int c = 0; c < 4; ++c) {
      float4 wv = Wl[i * 16 + 4 * q + c];
      a[c].x = fmaf(tv, wv.x, a[c].x); a[c].y = fmaf(tv, wv.y, a[c].y);
      a[c].z = fmaf(tv, wv.z, a[c].z); a[c].w = fmaf(tv, wv.w, a[c].w);
    }
  }
  if (FIRST) {  // own-term x @ W0
    __syncthreads();
    float4 own = make_float4(0.f, 0.f, 0.f, 0.f);
    if (node < n) own = unpack_h(hin[(size_t)node * 4 + q]);
    tl4[ln * 5 + q] = own;
    __syncthreads();
#pragma unroll 4
    for (int i = 0; i < 16; ++i) {
      float tv = tl[ln * 20 + i];
#pragma unroll
      for (int c = 0; c < 4; ++c) {
        float4 wv = W0l[i * 16 + 4 * q + c];
        a[c].x = fmaf(tv, wv.x, a[c].x); a[c].y = fmaf(tv, wv.y, a[c].y);
        a[c].z = fmaf(tv, wv.z, a[c].z); a[c].w = fmaf(tv, wv.w, a[c].w);
      }
    }
  }
  if (node >= n) return;

  if (LAST) {
#pragma unroll
    for (int c = 0; c < 4; ++c) {
      float4 b = bias4[4 * q + c];
      a[c].x += b.x; a[c].y += b.y; a[c].z += b.z; a[c].w += b.w;
      a[c].x = (a[c].x >= 0.f) ? a[c].x : 0.01f * a[c].x;
      a[c].y = (a[c].y >= 0.f) ? a[c].y : 0.01f * a[c].y;
      a[c].z = (a[c].z >= 0.f) ? a[c].z : 0.01f * a[c].z;
      a[c].w = (a[c].w >= 0.f) ? a[c].w : 0.01f * a[c].w;
      outbuf[(size_t)node * 16 + 4 * q + c] = pack_h(a[c]);  // activated h1, fp16
    }
  } else {
#pragma unroll
    for (int c = 0; c < 4; ++c) acch[(size_t)node * 16 + 4 * q + c] = pack_h(a[c]);
  }
}

extern "C" void kernel_launch(void* const* d_in, const int* in_sizes, int n_in,
                              void* d_out, int out_size, void* d_ws, size_t ws_size,
                              hipStream_t stream) {
  const float* x    = (const float*)d_in[0];
  const int*   ei   = (const int*)d_in[1];
  const float* ew   = (const float*)d_in[2];
  const float* W1   = (const float*)d_in[4];
  const float* b1   = (const float*)d_in[5];
  const float* W2   = (const float*)d_in[6];
  const float* b2   = (const float*)d_in[7];
  const float* Wout = (const float*)d_in[8];
  const float* bout = (const float*)d_in[9];
  float* out = (float*)d_out;

  const int N = in_sizes[0] / 16;
  const int E = in_sizes[2];
  const int* src = ei;
  const int* dst = ei + E;

  char* ws = (char*)d_ws;
  size_t off = 0;
  auto alloc = [&](size_t bytes) {
    char* p = ws + off;
    off = (off + bytes + 255) & ~(size_t)255;
    return p;
  };
  u64*     pack = (u64*)alloc((size_t)N * 8);
  float*   dinv = (float*)alloc((size_t)N * 4);
  int*     ptr  = (int*)alloc(((size_t)N + 1) * 4);
  int*     bsum = (int*)alloc(4096);
  int*     rank = (int*)alloc((size_t)E * 4);
  u32*     ep   = (u32*)alloc((size_t)E * 4);                // packed 4B edges
  ushort4* xh   = (ushort4*)alloc((size_t)N * 16 * 2);       // N x 16 fp16
  ushort4* hb0  = (ushort4*)alloc((size_t)N * 64 * 2);       // t ping
  ushort4* hb1  = (ushort4*)alloc((size_t)N * 64 * 2);       // t pong
  ushort4* hb2  = (ushort4*)alloc((size_t)N * 64 * 2);       // layer outputs
  ushort4* acch = (ushort4*)alloc((size_t)N * 64 * 2);       // fp16 acc

  hipMemsetAsync(pack, 0, (size_t)N * 8, stream);

  int gE = (E + 255) / 256;
  int gN = (N + 255) / 256;
  degcount_k<<<gE, 256, 0, stream>>>(dst, ew, pack, rank, E, (const float4*)x, xh, N * 4);
  scan_blocks<<<gN, 256, 0, stream>>>(pack, dinv, ptr, bsum, N);
  scan_sums<<<1, 512, 0, stream>>>(bsum, gN);
  scan_add<<<gN, 256, 0, stream>>>(ptr, bsum, N, E);
  fill_k<<<gE, 256, 0, stream>>>(src, dst, ew, dinv, ptr, rank, ep, E);

  int g4  = (N * 4 + 255) / 256;   // layer-1 fused (4 lanes/node)
  int g16 = (N * 16 + 255) / 256;  // F=64 fused (16 lanes/node)

  auto W1k = [&](int k) { return (const float4*)(W1 + (size_t)k * 1024); };
  auto W2k = [&](int l, int k) { return (const float4*)(W2 + ((size_t)l * 5 + k) * 4096); };

  // ---- Layer 1 (16 -> 64): acc in acch, t ping-pong hb0/hb1 (stride 4), h1 -> hb2 ----
  ptag16_k<true,  false><<<g4, 256, 0, stream>>>(ptr, ep, xh,  hb0, W1k(1), W1k(0), acch, nullptr, nullptr, N);
  ptag16_k<false, false><<<g4, 256, 0, stream>>>(ptr, ep, hb0, hb1, W1k(2), nullptr, acch, nullptr, nullptr, N);
  ptag16_k<false, false><<<g4, 256, 0, stream>>>(ptr, ep, hb1, hb0, W1k(3), nullptr, acch, nullptr, nullptr, N);
  ptag16_k<false, true ><<<g4, 256, 0, stream>>>(ptr, ep, hb0, nullptr, W1k(4), nullptr, acch,
                                                 (const float4*)b1, hb2, N);

  // ---- Layer 2 (64 -> 64): input hb2, t ping-pong hb0/hb1, h2 -> hb2 ----
  ptag64_k<true,  false, false><<<g16, 256, 0, stream>>>(ptr, ep, hb2, hb0, W2k(0,1), W2k(0,0), acch,
                                                         nullptr, nullptr, nullptr, nullptr, N);
  ptag64_k<false, false, false><<<g16, 256, 0, stream>>>(ptr, ep, hb0, hb1, W2k(0,2), nullptr, acch,
                                                         nullptr, nullptr, nullptr, nullptr, N);
  ptag64_k<false, false, false><<<g16, 256, 0, stream>>>(ptr, ep, hb1, hb0, W2k(0,3), nullptr, acch,
                                                         nullptr, nullptr, nullptr, nullptr, N);
  ptag64_k<false, true,  false><<<g16, 256, 0, stream>>>(ptr, ep, hb0, hb2, W2k(0,4), nullptr, acch,
                                                         (const float4*)b2, nullptr, nullptr, nullptr, N);

  // ---- Layer 3 (64 -> 64) + head: input hb2, head -> out ----
  ptag64_k<true,  false, false><<<g16, 256, 0, stream>>>(ptr, ep, hb2, hb0, W2k(1,1), W2k(1,0), acch,
                                                         nullptr, nullptr, nullptr, nullptr, N);
  ptag64_k<false, false, false><<<g16, 256, 0, stream>>>(ptr, ep, hb0, hb1, W2k(1,2), nullptr, acch,
                                                         nullptr, nullptr, nullptr, nullptr, N);
  ptag64_k<false, false, false><<<g16, 256, 0, stream>>>(ptr, ep, hb1, hb0, W2k(1,3), nullptr, acch,
                                                         nullptr, nullptr, nullptr, nullptr, N);
  ptag64_k<false, true,  true ><<<g16, 256, 0, stream>>>(ptr, ep, hb0, nullptr, W2k(1,4), nullptr, acch,
                                                         (const float4*)(b2 + 64), Wout, bout, out, N);
}

// Round 11
// 1169.987 us; speedup vs baseline: 1.0701x; 1.0074x over previous
//
#include <hip/hip_runtime.h>
#include <hip/hip_cooperative_groups.h>

namespace cg = cooperative_groups;

// ---------------------------------------------------------------------------
// TAGCN node regression: 3 TAGConv layers (K=4) + linear head, fp32 math.
// CSR-by-dst built once per launch (rank from degree atomic; fill atomic-free).
// fp16 inter-dispatch tensors, 4B packed edges [norm15|src17] (R10).
// R11: layers 2+3 (8 prop+mm phases + head) run in ONE persistent cooperative
// kernel — the per-layer accumulator lives in VGPRs across grid.sync(), so
// the ~150 MB fp16 acc round-trip and 7 launch boundaries disappear, and acc
// becomes fp32. Co-residency verified via occupancy query; R10's dispatch
// sequence kept as fallback. Atomic floor ~20 Gops/s -> degcount structural.
// ---------------------------------------------------------------------------

typedef unsigned long long u64;
typedef unsigned int u32;

__device__ __forceinline__ float h2f(unsigned short u) {
  _Float16 h;
  __builtin_memcpy(&h, &u, 2);
  return (float)h;
}
__device__ __forceinline__ unsigned short f2h(float f) {
  _Float16 h = (_Float16)f;  // RNE
  unsigned short u;
  __builtin_memcpy(&u, &h, 2);
  return u;
}
__device__ __forceinline__ ushort4 pack_h(float4 v) {
  ushort4 r;
  r.x = f2h(v.x); r.y = f2h(v.y); r.z = f2h(v.z); r.w = f2h(v.w);
  return r;
}
__device__ __forceinline__ float4 unpack_h(ushort4 u) {
  return make_float4(h2f(u.x), h2f(u.y), h2f(u.z), h2f(u.w));
}
// packed edge: [norm15 | src17]
__device__ __forceinline__ void dec_ep(u32 u, int& s, float& w) {
  s = (int)(u & 0x1FFFFu);
  w = h2f((unsigned short)(u >> 17));
}

// one 64-bit atomic per edge: [count:16 | sum_w Q16.32 fixed point:48]
// + fused x->fp16 convert (independent work, saves a dispatch)
__global__ void degcount_k(const int* __restrict__ dst, const float* __restrict__ w,
                           u64* __restrict__ pack, int* __restrict__ rank, int E,
                           const float4* __restrict__ x4, ushort4* __restrict__ xh, int n4) {
  int e = blockIdx.x * blockDim.x + threadIdx.x;
  if (e < n4) xh[e] = pack_h(x4[e]);
  if (e >= E) return;
  int d = dst[e];
  u64 v = ((u64)1 << 48) | (u64)((double)w[e] * 4294967296.0);
  u64 old = atomicAdd(&pack[d], v);
  rank[e] = (int)(old >> 48);
}

// scan (256/block) fused with degree decode -> dinv
__global__ void scan_blocks(const u64* __restrict__ pack, float* __restrict__ dinv,
                            int* __restrict__ ptr, int* __restrict__ bsum, int n) {
  __shared__ int s[256];
  int tid = threadIdx.x;
  int i = blockIdx.x * 256 + tid;
  int v = 0;
  if (i < n) {
    u64 p = pack[i];
    v = (int)(p >> 48);
    float d = (float)((double)(p & 0xFFFFFFFFFFFFULL) * (1.0 / 4294967296.0));
    dinv[i] = (d > 0.f) ? rsqrtf(fmaxf(d, 1e-30f)) : 0.f;
  }
  s[tid] = v;
  __syncthreads();
#pragma unroll
  for (int off = 1; off < 256; off <<= 1) {
    int t = (tid >= off) ? s[tid - off] : 0;
    __syncthreads();
    s[tid] += t;
    __syncthreads();
  }
  if (i < n) ptr[i] = s[tid] - v;
  if (tid == 255) bsum[blockIdx.x] = s[255];
}

__global__ void scan_sums(int* __restrict__ bsum, int nb) {
  __shared__ int s[512];
  int tid = threadIdx.x;
  int v = (tid < nb) ? bsum[tid] : 0;
  s[tid] = v;
  __syncthreads();
#pragma unroll
  for (int off = 1; off < 512; off <<= 1) {
    int t = (tid >= off) ? s[tid - off] : 0;
    __syncthreads();
    s[tid] += t;
    __syncthreads();
  }
  if (tid < nb) bsum[tid] = s[tid] - v;
}

__global__ void scan_add(int* __restrict__ ptr, const int* __restrict__ bsum, int n, int E) {
  int i = blockIdx.x * blockDim.x + threadIdx.x;
  if (i < n) ptr[i] += bsum[i >> 8];
  if (i == 0) ptr[n] = E;
}

// scatter edges into CSR slots (atomic-free); payload = [norm15|src17] u32
__global__ void fill_k(const int* __restrict__ src, const int* __restrict__ dst,
                       const float* __restrict__ w, const float* __restrict__ dinv,
                       const int* __restrict__ ptr, const int* __restrict__ rank,
                       u32* __restrict__ ep, int E) {
  int e = blockIdx.x * blockDim.x + threadIdx.x;
  if (e >= E) return;
  int s = src[e], d = dst[e];
  float nv = dinv[s] * w[e] * dinv[d];
  int pos = ptr[d] + rank[e];
  ep[pos] = ((u32)f2h(nv) << 17) | (u32)s;  // norm>=0 -> sign bit free
}

// gather t[f4] = sum_e w_e * fp16(hin[src_e][f4]); 2-edge unroll, 4B edges
template <int F4>
__device__ __forceinline__ float4 gather(const int* __restrict__ ptr, const u32* __restrict__ ep,
                                         const ushort4* __restrict__ hin, int node, int f4) {
  int e0 = ptr[node], e1 = ptr[node + 1];
  float4 a = make_float4(0.f, 0.f, 0.f, 0.f);
  int e = e0;
  if ((e & 1) && e < e1) {
    int s0; float w0; dec_ep(ep[e], s0, w0);
    ushort4 h = hin[(size_t)s0 * F4 + f4];
    a.x = fmaf(w0, h2f(h.x), a.x); a.y = fmaf(w0, h2f(h.y), a.y);
    a.z = fmaf(w0, h2f(h.z), a.z); a.w = fmaf(w0, h2f(h.w), a.w);
    ++e;
  }
  for (; e + 1 < e1; e += 2) {
    uint2 p = *(const uint2*)(ep + e);  // 2 edges, 8B aligned
    int s0, s1; float w0, w1;
    dec_ep(p.x, s0, w0);
    dec_ep(p.y, s1, w1);
    ushort4 h0 = hin[(size_t)s0 * F4 + f4];
    ushort4 h1 = hin[(size_t)s1 * F4 + f4];
    a.x = fmaf(w0, h2f(h0.x), a.x); a.y = fmaf(w0, h2f(h0.y), a.y);
    a.z = fmaf(w0, h2f(h0.z), a.z); a.w = fmaf(w0, h2f(h0.w), a.w);
    a.x = fmaf(w1, h2f(h1.x), a.x); a.y = fmaf(w1, h2f(h1.y), a.y);
    a.z = fmaf(w1, h2f(h1.z), a.z); a.w = fmaf(w1, h2f(h1.w), a.w);
  }
  if (e < e1) {
    int s0; float w0; dec_ep(ep[e], s0, w0);
    ushort4 h = hin[(size_t)s0 * F4 + f4];
    a.x = fmaf(w0, h2f(h.x), a.x); a.y = fmaf(w0, h2f(h.y), a.y);
    a.z = fmaf(w0, h2f(h.z), a.z); a.w = fmaf(w0, h2f(h.w), a.w);
  }
  return a;
}

// scalar-broadcast mm accumulate: a += t(group ln) @ W  (28-VGPR shape, R6).
// t element i of group ln lives at word ln*64 + (((i>>2)^ln)<<2 | (i&3)).
__device__ __forceinline__ void mm_acc(const float* __restrict__ tl, const float4* __restrict__ Wl,
                                       int ln, int j4, float4& a) {
#pragma unroll 8
  for (int i = 0; i < 64; ++i) {
    float tv = tl[ln * 64 + ((((i >> 2) ^ ln) << 2) | (i & 3))];
    float4 wv = Wl[i * 16 + j4];
    a.x = fmaf(tv, wv.x, a.x); a.y = fmaf(tv, wv.y, a.y);
    a.z = fmaf(tv, wv.z, a.z); a.w = fmaf(tv, wv.w, a.w);
  }
}

// ---------- persistent cooperative kernel: layers 2+3 (8 phases) + head ----------
// Each block owns the same NC=5 chunks of 16 nodes across all phases; the
// layer accumulator (acc[NC], fp32) lives in VGPRs across grid.sync().
// LDS = 16K W + 4K tile = 20480 B. Phases: k=1..4 per layer; k=1 adds the
// own-term (W0) second pass; k=4 applies bias+leaky and writes hb2 (L2) or
// the head reduction to out (L3).
__global__ __launch_bounds__(256) void mega_k(
    const int* __restrict__ ptr, const u32* __restrict__ ep,
    ushort4* __restrict__ hb0, ushort4* __restrict__ hb1, ushort4* __restrict__ hb2,
    const float* __restrict__ W2, const float* __restrict__ b2,
    const float* __restrict__ Wout, const float* __restrict__ bout,
    float* __restrict__ outv, int n) {
  cg::grid_group grid = cg::this_grid();
  __shared__ float4 Wl[1024];
  __shared__ float4 tl4[256];
  const float* tl = (const float*)tl4;
  const int tid = threadIdx.x, j4 = tid & 15, ln = tid >> 4;
  const int nb = (int)gridDim.x;
  constexpr int NC = 5;
  float4 acc[NC];

  for (int L = 0; L < 2; ++L) {
    const float* WL = W2 + (size_t)L * 5 * 4096;
#pragma unroll
    for (int c = 0; c < NC; ++c) acc[c] = make_float4(0.f, 0.f, 0.f, 0.f);
    for (int k = 1; k <= 4; ++k) {
      const ushort4* gsrc = (k == 1) ? hb2 : ((k == 3) ? hb1 : hb0);
      ushort4* gdst = (k == 2) ? hb1 : hb0;
      const bool last = (k == 4);
      const float4* Wk4 = (const float4*)(WL + (size_t)k * 4096);
      __syncthreads();
      for (int i = tid; i < 1024; i += 256) Wl[i] = Wk4[i];
#pragma unroll
      for (int c = 0; c < NC; ++c) {
        int node = (c * nb + (int)blockIdx.x) * 16 + ln;
        float4 t = make_float4(0.f, 0.f, 0.f, 0.f);
        if (node < n) {
          t = gather<16>(ptr, ep, gsrc, node, j4);
          if (!last) gdst[(size_t)node * 16 + j4] = pack_h(t);
        }
        __syncthreads();  // prior chunk's mm done reading tile (and Wl visible)
        tl4[ln * 16 + (j4 ^ ln)] = t;
        __syncthreads();
        mm_acc(tl, Wl, ln, j4, acc[c]);
      }
      if (k == 1) {  // own-term h_in @ W0 (h_in = hb2 for both layers)
        const float4* W04 = (const float4*)WL;
        __syncthreads();
        for (int i = tid; i < 1024; i += 256) Wl[i] = W04[i];
#pragma unroll
        for (int c = 0; c < NC; ++c) {
          int node = (c * nb + (int)blockIdx.x) * 16 + ln;
          float4 own = make_float4(0.f, 0.f, 0.f, 0.f);
          if (node < n) own = unpack_h(hb2[(size_t)node * 16 + j4]);
          __syncthreads();
          tl4[ln * 16 + (j4 ^ ln)] = own;
          __syncthreads();
          mm_acc(tl, Wl, ln, j4, acc[c]);
        }
      }
      if (last) {  // epilogue: bias + leaky, then layer output or head
        const float4* bias4 = (const float4*)(b2 + (size_t)L * 64);
#pragma unroll
        for (int c = 0; c < NC; ++c) {
          int node = (c * nb + (int)blockIdx.x) * 16 + ln;
          if (node >= n) continue;
          float4 a = acc[c];
          float4 b = bias4[j4];
          a.x += b.x; a.y += b.y; a.z += b.z; a.w += b.w;
          a.x = (a.x >= 0.f) ? a.x : 0.01f * a.x;
          a.y = (a.y >= 0.f) ? a.y : 0.01f * a.y;
          a.z = (a.z >= 0.f) ? a.z : 0.01f * a.z;
          a.w = (a.w >= 0.f) ? a.w : 0.01f * a.w;
          if (L == 0) {
            hb2[(size_t)node * 16 + j4] = pack_h(a);
          } else {
            float v = a.x * Wout[4 * j4] + a.y * Wout[4 * j4 + 1] +
                      a.z * Wout[4 * j4 + 2] + a.w * Wout[4 * j4 + 3];
            v += __shfl_down(v, 8, 16);
            v += __shfl_down(v, 4, 16);
            v += __shfl_down(v, 2, 16);
            v += __shfl_down(v, 1, 16);
            if (j4 == 0) outv[node] = v + bout[0];
          }
        }
      }
      __threadfence();  // make gdst/hb2 stores device-visible (cross-XCD)
      grid.sync();
    }
  }
}

// ---------- fallback fused prop + matmul, F=64 (R10, fp16 acc) ----------
template <bool FIRST, bool LAST, bool HEAD>
__launch_bounds__(256)
__global__ void ptag64_k(const int* __restrict__ ptr, const u32* __restrict__ ep,
                         const ushort4* __restrict__ hin, ushort4* __restrict__ hout,
                         const float4* __restrict__ Wk4, const float4* __restrict__ W04,
                         ushort4* __restrict__ acch, const float4* __restrict__ bias4,
                         const float* __restrict__ Wout, const float* __restrict__ bout,
                         float* __restrict__ outv, int n) {
  __shared__ float4 Wl[1024];
  __shared__ float4 tl4[256];
  const float* tl = (const float*)tl4;
  int tid = threadIdx.x;
  for (int i = tid; i < 1024; i += 256) Wl[i] = Wk4[i];
  int gid = blockIdx.x * 256 + tid;
  int node = gid >> 4, j4 = gid & 15, ln = tid >> 4;

  float4 t = make_float4(0.f, 0.f, 0.f, 0.f);
  if (node < n) {
    t = gather<16>(ptr, ep, hin, node, j4);
    if (!LAST) hout[(size_t)node * 16 + j4] = pack_h(t);
  }
  tl4[ln * 16 + (j4 ^ ln)] = t;
  __syncthreads();

  float4 a = make_float4(0.f, 0.f, 0.f, 0.f);
  if (!FIRST && node < n) a = unpack_h(acch[(size_t)node * 16 + j4]);
  mm_acc(tl, Wl, ln, j4, a);
  if (FIRST) {
    __syncthreads();
    for (int i = tid; i < 1024; i += 256) Wl[i] = W04[i];
    float4 own = make_float4(0.f, 0.f, 0.f, 0.f);
    if (node < n) own = unpack_h(hin[(size_t)node * 16 + j4]);
    tl4[ln * 16 + (j4 ^ ln)] = own;
    __syncthreads();
    mm_acc(tl, Wl, ln, j4, a);
  }
  if (node >= n) return;

  if (LAST) {
    float4 b = bias4[j4];
    a.x += b.x; a.y += b.y; a.z += b.z; a.w += b.w;
    a.x = (a.x >= 0.f) ? a.x : 0.01f * a.x;
    a.y = (a.y >= 0.f) ? a.y : 0.01f * a.y;
    a.z = (a.z >= 0.f) ? a.z : 0.01f * a.z;
    a.w = (a.w >= 0.f) ? a.w : 0.01f * a.w;
    if (HEAD) {
      float v = a.x * Wout[4 * j4] + a.y * Wout[4 * j4 + 1] +
                a.z * Wout[4 * j4 + 2] + a.w * Wout[4 * j4 + 3];
      v += __shfl_down(v, 8, 16);
      v += __shfl_down(v, 4, 16);
      v += __shfl_down(v, 2, 16);
      v += __shfl_down(v, 1, 16);
      if (j4 == 0) outv[node] = v + bout[0];
    } else {
      hout[(size_t)node * 16 + j4] = pack_h(a);
    }
  } else {
    acch[(size_t)node * 16 + j4] = pack_h(a);
  }
}

// ---------- fused prop + matmul, layer 1: F_in=16 (4 lanes/node) ----------
template <bool FIRST, bool LAST>
__launch_bounds__(256)
__global__ void ptag16_k(const int* __restrict__ ptr, const u32* __restrict__ ep,
                         const ushort4* __restrict__ hin, ushort4* __restrict__ hout,
                         const float4* __restrict__ Wk4, const float4* __restrict__ W04,
                         ushort4* __restrict__ acch, const float4* __restrict__ bias4,
                         ushort4* __restrict__ outbuf, int n) {
  __shared__ float4 Wl[256];
  __shared__ float4 W0l[FIRST ? 256 : 1];
  __shared__ float4 tl4[64 * 5];
  const float* tl = (const float*)tl4;
  int tid = threadIdx.x;
  Wl[tid] = Wk4[tid];
  if (FIRST) W0l[tid] = W04[tid];
  int gid = blockIdx.x * 256 + tid;
  int node = gid >> 2, q = tid & 3, ln = tid >> 2;

  float4 t = make_float4(0.f, 0.f, 0.f, 0.f);
  if (node < n) {
    t = gather<4>(ptr, ep, hin, node, q);
    if (!LAST) hout[(size_t)node * 4 + q] = pack_h(t);
  }
  tl4[ln * 5 + q] = t;
  __syncthreads();

  float4 a[4];
#pragma unroll
  for (int c = 0; c < 4; ++c) a[c] = make_float4(0.f, 0.f, 0.f, 0.f);
  if (!FIRST && node < n) {
#pragma unroll
    for (int c = 0; c < 4; ++c) a[c] = unpack_h(acch[(size_t)node * 16 + 4 * q + c]);
  }
#pragma unroll 4
  for (int i = 0; i < 16; ++i) {
    float tv = tl[ln * 20 + i];
#pragma unroll
    for (int c = 0; c < 4; ++c) {
      float4 wv = Wl[i * 16 + 4 * q + c];
      a[c].x = fmaf(tv, wv.x, a[c].x); a[c].y = fmaf(tv, wv.y, a[c].y);
      a[c].z = fmaf(tv, wv.z, a[c].z); a[c].w = fmaf(tv, wv.w, a[c].w);
    }
  }
  if (FIRST) {
    __syncthreads();
    float4 own = make_float4(0.f, 0.f, 0.f, 0.f);
    if (node < n) own = unpack_h(hin[(size_t)node * 4 + q]);
    tl4[ln * 5 + q] = own;
    __syncthreads();
#pragma unroll 4
    for (int i = 0; i < 16; ++i) {
      float tv = tl[ln * 20 + i];
#pragma unroll
      for (int c = 0; c < 4; ++c) {
        float4 wv = W0l[i * 16 + 4 * q + c];
        a[c].x = fmaf(tv, wv.x, a[c].x); a[c].y = fmaf(tv, wv.y, a[c].y);
        a[c].z = fmaf(tv, wv.z, a[c].z); a[c].w = fmaf(tv, wv.w, a[c].w);
      }
    }
  }
  if (node >= n) return;

  if (LAST) {
#pragma unroll
    for (int c = 0; c < 4; ++c) {
      float4 b = bias4[4 * q + c];
      a[c].x += b.x; a[c].y += b.y; a[c].z += b.z; a[c].w += b.w;
      a[c].x = (a[c].x >= 0.f) ? a[c].x : 0.01f * a[c].x;
      a[c].y = (a[c].y >= 0.f) ? a[c].y : 0.01f * a[c].y;
      a[c].z = (a[c].z >= 0.f) ? a[c].z : 0.01f * a[c].z;
      a[c].w = (a[c].w >= 0.f) ? a[c].w : 0.01f * a[c].w;
      outbuf[(size_t)node * 16 + 4 * q + c] = pack_h(a[c]);
    }
  } else {
#pragma unroll
    for (int c = 0; c < 4; ++c) acch[(size_t)node * 16 + 4 * q + c] = pack_h(a[c]);
  }
}

extern "C" void kernel_launch(void* const* d_in, const int* in_sizes, int n_in,
                              void* d_out, int out_size, void* d_ws, size_t ws_size,
                              hipStream_t stream) {
  const float* x    = (const float*)d_in[0];
  const int*   ei   = (const int*)d_in[1];
  const float* ew   = (const float*)d_in[2];
  const float* W1   = (const float*)d_in[4];
  const float* b1   = (const float*)d_in[5];
  const float* W2   = (const float*)d_in[6];
  const float* b2   = (const float*)d_in[7];
  const float* Wout = (const float*)d_in[8];
  const float* bout = (const float*)d_in[9];
  float* out = (float*)d_out;

  const int N = in_sizes[0] / 16;
  const int E = in_sizes[2];
  const int* src = ei;
  const int* dst = ei + E;

  char* ws = (char*)d_ws;
  size_t off = 0;
  auto alloc = [&](size_t bytes) {
    char* p = ws + off;
    off = (off + bytes + 255) & ~(size_t)255;
    return p;
  };
  u64*     pack = (u64*)alloc((size_t)N * 8);
  float*   dinv = (float*)alloc((size_t)N * 4);
  int*     ptr  = (int*)alloc(((size_t)N + 1) * 4);
  int*     bsum = (int*)alloc(4096);
  int*     rank = (int*)alloc((size_t)E * 4);
  u32*     ep   = (u32*)alloc((size_t)E * 4);                // packed 4B edges
  ushort4* xh   = (ushort4*)alloc((size_t)N * 16 * 2);       // N x 16 fp16
  ushort4* hb0  = (ushort4*)alloc((size_t)N * 64 * 2);       // t ping
  ushort4* hb1  = (ushort4*)alloc((size_t)N * 64 * 2);       // t pong
  ushort4* hb2  = (ushort4*)alloc((size_t)N * 64 * 2);       // layer outputs
  ushort4* acch = (ushort4*)alloc((size_t)N * 64 * 2);       // fp16 acc (layer1/fallback)

  hipMemsetAsync(pack, 0, (size_t)N * 8, stream);

  int gE = (E + 255) / 256;
  int gN = (N + 255) / 256;
  degcount_k<<<gE, 256, 0, stream>>>(dst, ew, pack, rank, E, (const float4*)x, xh, N * 4);
  scan_blocks<<<gN, 256, 0, stream>>>(pack, dinv, ptr, bsum, N);
  scan_sums<<<1, 512, 0, stream>>>(bsum, gN);
  scan_add<<<gN, 256, 0, stream>>>(ptr, bsum, N, E);
  fill_k<<<gE, 256, 0, stream>>>(src, dst, ew, dinv, ptr, rank, ep, E);

  int g4  = (N * 4 + 255) / 256;   // layer-1 fused (4 lanes/node)
  int g16 = (N * 16 + 255) / 256;  // fallback F=64 fused

  auto W1k = [&](int k) { return (const float4*)(W1 + (size_t)k * 1024); };
  auto W2k = [&](int l, int k) { return (const float4*)(W2 + ((size_t)l * 5 + k) * 4096); };

  // ---- Layer 1 (16 -> 64): acc in acch, t ping-pong hb0/hb1, h1 -> hb2 ----
  ptag16_k<true,  false><<<g4, 256, 0, stream>>>(ptr, ep, xh,  hb0, W1k(1), W1k(0), acch, nullptr, nullptr, N);
  ptag16_k<false, false><<<g4, 256, 0, stream>>>(ptr, ep, hb0, hb1, W1k(2), nullptr, acch, nullptr, nullptr, N);
  ptag16_k<false, false><<<g4, 256, 0, stream>>>(ptr, ep, hb1, hb0, W1k(3), nullptr, acch, nullptr, nullptr, N);
  ptag16_k<false, true ><<<g4, 256, 0, stream>>>(ptr, ep, hb0, nullptr, W1k(4), nullptr, acch,
                                                 (const float4*)b1, hb2, N);

  // ---- Layers 2+3 + head: persistent cooperative kernel (preferred) ----
  int maxB = 0;
  (void)hipOccupancyMaxActiveBlocksPerMultiprocessor(&maxB, mega_k, 256, 0);
  int grid = maxB * 256;  // 256 CUs on MI355X
  if (grid > 2048) grid = 2048;
  const bool coop_ok = (grid > 0) && ((size_t)grid * 16 * 5 >= (size_t)N);

  if (coop_ok) {
    const int* ptrA = ptr; const u32* epA = ep;
    ushort4 *h0A = hb0, *h1A = hb1, *h2A = hb2;
    const float *W2A = W2, *b2A = b2, *WoA = Wout, *boA = bout;
    float* outA = out; int nA = N;
    void* args[] = {&ptrA, &epA, &h0A, &h1A, &h2A, &W2A, &b2A, &WoA, &boA, &outA, &nA};
    hipLaunchCooperativeKernel((void*)mega_k, dim3(grid), dim3(256), args, 0, stream);
  } else {
    // fallback: R10's dispatch sequence
    ptag64_k<true,  false, false><<<g16, 256, 0, stream>>>(ptr, ep, hb2, hb0, W2k(0,1), W2k(0,0), acch,
                                                           nullptr, nullptr, nullptr, nullptr, N);
    ptag64_k<false, false, false><<<g16, 256, 0, stream>>>(ptr, ep, hb0, hb1, W2k(0,2), nullptr, acch,
                                                           nullptr, nullptr, nullptr, nullptr, N);
    ptag64_k<false, false, false><<<g16, 256, 0, stream>>>(ptr, ep, hb1, hb0, W2k(0,3), nullptr, acch,
                                                           nullptr, nullptr, nullptr, nullptr, N);
    ptag64_k<false, true,  false><<<g16, 256, 0, stream>>>(ptr, ep, hb0, hb2, W2k(0,4), nullptr, acch,
                                                           (const float4*)b2, nullptr, nullptr, nullptr, N);
    ptag64_k<true,  false, false><<<g16, 256, 0, stream>>>(ptr, ep, hb2, hb0, W2k(1,1), W2k(1,0), acch,
                                                           nullptr, nullptr, nullptr, nullptr, N);
    ptag64_k<false, false, false><<<g16, 256, 0, stream>>>(ptr, ep, hb0, hb1, W2k(1,2), nullptr, acch,
                                                           nullptr, nullptr, nullptr, nullptr, N);
    ptag64_k<false, false, false><<<g16, 256, 0, stream>>>(ptr, ep, hb1, hb0, W2k(1,3), nullptr, acch,
                                                           nullptr, nullptr, nullptr, nullptr, N);
    ptag64_k<false, true,  true ><<<g16, 256, 0, stream>>>(ptr, ep, hb0, nullptr, W2k(1,4), nullptr, acch,
                                                           (const float4*)(b2 + 64), Wout, bout, out, N);
  }
}

// Round 12
// 1162.668 us; speedup vs baseline: 1.0769x; 1.0063x over previous
//
#include <hip/hip_runtime.h>
#include <hip/hip_cooperative_groups.h>

namespace cg = cooperative_groups;

// ---------------------------------------------------------------------------
// TAGCN node regression: 3 TAGConv layers (K=4) + linear head, fp32 math.
// CSR-by-dst built once per launch (rank from degree atomic; fill atomic-free).
// fp16 inter-dispatch tensors, 4B packed edges [norm15|src17] (R10).
// R12: persistent cooperative kernel for layers 2+3, restructured so the
// t-tile is wave-private (it always was — ln=tid>>4 groups 4 slots/wave; no
// block barrier needed for tile RAW). Barriers only around Wl loads; waves
// stream chunks independently (R6's proven 28-VGPR mm shape). fp32 acc lives
// in VGPRs across grid.sync() -> acc round-trip + 7 launch gaps eliminated.
// NC templated {4,5,7}; runtime occupancy query picks instance; R10 fallback.
// Atomic floor ~20 Gops/s -> degcount ~155us structural.
// ---------------------------------------------------------------------------

typedef unsigned long long u64;
typedef unsigned int u32;

__device__ __forceinline__ float h2f(unsigned short u) {
  _Float16 h;
  __builtin_memcpy(&h, &u, 2);
  return (float)h;
}
__device__ __forceinline__ unsigned short f2h(float f) {
  _Float16 h = (_Float16)f;  // RNE
  unsigned short u;
  __builtin_memcpy(&u, &h, 2);
  return u;
}
__device__ __forceinline__ ushort4 pack_h(float4 v) {
  ushort4 r;
  r.x = f2h(v.x); r.y = f2h(v.y); r.z = f2h(v.z); r.w = f2h(v.w);
  return r;
}
__device__ __forceinline__ float4 unpack_h(ushort4 u) {
  return make_float4(h2f(u.x), h2f(u.y), h2f(u.z), h2f(u.w));
}
// packed edge: [norm15 | src17]
__device__ __forceinline__ void dec_ep(u32 u, int& s, float& w) {
  s = (int)(u & 0x1FFFFu);
  w = h2f((unsigned short)(u >> 17));
}

// one 64-bit atomic per edge: [count:16 | sum_w Q16.32 fixed point:48]
// + fused x->fp16 convert
__global__ void degcount_k(const int* __restrict__ dst, const float* __restrict__ w,
                           u64* __restrict__ pack, int* __restrict__ rank, int E,
                           const float4* __restrict__ x4, ushort4* __restrict__ xh, int n4) {
  int e = blockIdx.x * blockDim.x + threadIdx.x;
  if (e < n4) xh[e] = pack_h(x4[e]);
  if (e >= E) return;
  int d = dst[e];
  u64 v = ((u64)1 << 48) | (u64)((double)w[e] * 4294967296.0);
  u64 old = atomicAdd(&pack[d], v);
  rank[e] = (int)(old >> 48);
}

// scan (256/block) fused with degree decode -> dinv
__global__ void scan_blocks(const u64* __restrict__ pack, float* __restrict__ dinv,
                            int* __restrict__ ptr, int* __restrict__ bsum, int n) {
  __shared__ int s[256];
  int tid = threadIdx.x;
  int i = blockIdx.x * 256 + tid;
  int v = 0;
  if (i < n) {
    u64 p = pack[i];
    v = (int)(p >> 48);
    float d = (float)((double)(p & 0xFFFFFFFFFFFFULL) * (1.0 / 4294967296.0));
    dinv[i] = (d > 0.f) ? rsqrtf(fmaxf(d, 1e-30f)) : 0.f;
  }
  s[tid] = v;
  __syncthreads();
#pragma unroll
  for (int off = 1; off < 256; off <<= 1) {
    int t = (tid >= off) ? s[tid - off] : 0;
    __syncthreads();
    s[tid] += t;
    __syncthreads();
  }
  if (i < n) ptr[i] = s[tid] - v;
  if (tid == 255) bsum[blockIdx.x] = s[255];
}

__global__ void scan_sums(int* __restrict__ bsum, int nb) {
  __shared__ int s[512];
  int tid = threadIdx.x;
  int v = (tid < nb) ? bsum[tid] : 0;
  s[tid] = v;
  __syncthreads();
#pragma unroll
  for (int off = 1; off < 512; off <<= 1) {
    int t = (tid >= off) ? s[tid - off] : 0;
    __syncthreads();
    s[tid] += t;
    __syncthreads();
  }
  if (tid < nb) bsum[tid] = s[tid] - v;
}

__global__ void scan_add(int* __restrict__ ptr, const int* __restrict__ bsum, int n, int E) {
  int i = blockIdx.x * blockDim.x + threadIdx.x;
  if (i < n) ptr[i] += bsum[i >> 8];
  if (i == 0) ptr[n] = E;
}

// scatter edges into CSR slots (atomic-free); payload = [norm15|src17] u32
__global__ void fill_k(const int* __restrict__ src, const int* __restrict__ dst,
                       const float* __restrict__ w, const float* __restrict__ dinv,
                       const int* __restrict__ ptr, const int* __restrict__ rank,
                       u32* __restrict__ ep, int E) {
  int e = blockIdx.x * blockDim.x + threadIdx.x;
  if (e >= E) return;
  int s = src[e], d = dst[e];
  float nv = dinv[s] * w[e] * dinv[d];
  int pos = ptr[d] + rank[e];
  ep[pos] = ((u32)f2h(nv) << 17) | (u32)s;  // norm>=0 -> sign bit free
}

// gather t[f4] = sum_e w_e * fp16(hin[src_e][f4]); 2-edge unroll, 4B edges
template <int F4>
__device__ __forceinline__ float4 gather(const int* __restrict__ ptr, const u32* __restrict__ ep,
                                         const ushort4* __restrict__ hin, int node, int f4) {
  int e0 = ptr[node], e1 = ptr[node + 1];
  float4 a = make_float4(0.f, 0.f, 0.f, 0.f);
  int e = e0;
  if ((e & 1) && e < e1) {
    int s0; float w0; dec_ep(ep[e], s0, w0);
    ushort4 h = hin[(size_t)s0 * F4 + f4];
    a.x = fmaf(w0, h2f(h.x), a.x); a.y = fmaf(w0, h2f(h.y), a.y);
    a.z = fmaf(w0, h2f(h.z), a.z); a.w = fmaf(w0, h2f(h.w), a.w);
    ++e;
  }
  for (; e + 1 < e1; e += 2) {
    uint2 p = *(const uint2*)(ep + e);  // 2 edges, 8B aligned
    int s0, s1; float w0, w1;
    dec_ep(p.x, s0, w0);
    dec_ep(p.y, s1, w1);
    ushort4 h0 = hin[(size_t)s0 * F4 + f4];
    ushort4 h1 = hin[(size_t)s1 * F4 + f4];
    a.x = fmaf(w0, h2f(h0.x), a.x); a.y = fmaf(w0, h2f(h0.y), a.y);
    a.z = fmaf(w0, h2f(h0.z), a.z); a.w = fmaf(w0, h2f(h0.w), a.w);
    a.x = fmaf(w1, h2f(h1.x), a.x); a.y = fmaf(w1, h2f(h1.y), a.y);
    a.z = fmaf(w1, h2f(h1.z), a.z); a.w = fmaf(w1, h2f(h1.w), a.w);
  }
  if (e < e1) {
    int s0; float w0; dec_ep(ep[e], s0, w0);
    ushort4 h = hin[(size_t)s0 * F4 + f4];
    a.x = fmaf(w0, h2f(h.x), a.x); a.y = fmaf(w0, h2f(h.y), a.y);
    a.z = fmaf(w0, h2f(h.z), a.z); a.w = fmaf(w0, h2f(h.w), a.w);
  }
  return a;
}

// scalar-broadcast mm accumulate: a += t(slot ln) @ W  (R6's 28-VGPR shape).
// t element i of slot ln lives at word ln*64 + (((i>>2)^ln)<<2 | (i&3)).
// Tile rows are WAVE-PRIVATE (ln = tid>>4): same-wave LDS RAW needs no barrier.
__device__ __forceinline__ void mm_acc(const float* __restrict__ tl, const float4* __restrict__ Wl,
                                       int ln, int j4, float4& a) {
#pragma unroll 8
  for (int i = 0; i < 64; ++i) {
    float tv = tl[ln * 64 + ((((i >> 2) ^ ln) << 2) | (i & 3))];
    float4 wv = Wl[i * 16 + j4];
    a.x = fmaf(tv, wv.x, a.x); a.y = fmaf(tv, wv.y, a.y);
    a.z = fmaf(tv, wv.z, a.z); a.w = fmaf(tv, wv.w, a.w);
  }
}

// ---------- persistent cooperative kernel: layers 2+3 + head ----------
// Each block owns NC chunks of 16 nodes across all phases; acc in VGPRs.
// LDS = 16K W + 4K wave-private tile = 20480 B. Barriers only around Wl.
template <int NC>
__global__ __launch_bounds__(256) void mega_k(
    const int* __restrict__ ptr, const u32* __restrict__ ep,
    ushort4* __restrict__ hb0, ushort4* __restrict__ hb1, ushort4* __restrict__ hb2,
    const float* __restrict__ W2, const float* __restrict__ b2,
    const float* __restrict__ Wout, const float* __restrict__ bout,
    float* __restrict__ outv, int n) {
  cg::grid_group grid = cg::this_grid();
  __shared__ float4 Wl[1024];
  __shared__ float4 tl4[256];
  const float* tl = (const float*)tl4;
  const int tid = threadIdx.x, j4 = tid & 15, ln = tid >> 4;
  const int nb = (int)gridDim.x;
  float4 acc[NC];

  for (int L = 0; L < 2; ++L) {
    const float* WL = W2 + (size_t)L * 5 * 4096;
#pragma unroll
    for (int c = 0; c < NC; ++c) acc[c] = make_float4(0.f, 0.f, 0.f, 0.f);

    // ---- own-term pass: acc += h_in @ W0  (h_in = hb2 for both layers) ----
    {
      const float4* W04 = (const float4*)WL;
      for (int i = tid; i < 1024; i += 256) Wl[i] = W04[i];
      __syncthreads();  // Wl visible to all waves
#pragma unroll
      for (int c = 0; c < NC; ++c) {
        int node = (c * nb + (int)blockIdx.x) * 16 + ln;
        float4 own = make_float4(0.f, 0.f, 0.f, 0.f);
        if (node < n) own = unpack_h(hb2[(size_t)node * 16 + j4]);
        tl4[ln * 16 + (j4 ^ ln)] = own;   // wave-private row, no barrier
        mm_acc(tl, Wl, ln, j4, acc[c]);
      }
      __syncthreads();  // all waves done reading Wl(W0) before reload
    }

    // ---- k = 1..4 propagation phases ----
    for (int k = 1; k <= 4; ++k) {
      const ushort4* gsrc = (k == 1) ? hb2 : ((k == 3) ? hb1 : hb0);
      ushort4* gdst = (k == 2) ? hb1 : hb0;
      const bool last = (k == 4);
      const float4* Wk4 = (const float4*)(WL + (size_t)k * 4096);
      for (int i = tid; i < 1024; i += 256) Wl[i] = Wk4[i];
      __syncthreads();
#pragma unroll
      for (int c = 0; c < NC; ++c) {
        int node = (c * nb + (int)blockIdx.x) * 16 + ln;
        float4 t = make_float4(0.f, 0.f, 0.f, 0.f);
        if (node < n) {
          t = gather<16>(ptr, ep, gsrc, node, j4);
          if (!last) gdst[(size_t)node * 16 + j4] = pack_h(t);
        }
        tl4[ln * 16 + (j4 ^ ln)] = t;     // wave-private, no barrier
        mm_acc(tl, Wl, ln, j4, acc[c]);
      }
      if (last) {  // epilogue: bias + leaky -> layer output (L0) or head (L1)
        const float4* bias4 = (const float4*)(b2 + (size_t)L * 64);
#pragma unroll
        for (int c = 0; c < NC; ++c) {
          int node = (c * nb + (int)blockIdx.x) * 16 + ln;
          if (node >= n) continue;
          float4 a = acc[c];
          float4 b = bias4[j4];
          a.x += b.x; a.y += b.y; a.z += b.z; a.w += b.w;
          a.x = (a.x >= 0.f) ? a.x : 0.01f * a.x;
          a.y = (a.y >= 0.f) ? a.y : 0.01f * a.y;
          a.z = (a.z >= 0.f) ? a.z : 0.01f * a.z;
          a.w = (a.w >= 0.f) ? a.w : 0.01f * a.w;
          if (L == 0) {
            hb2[(size_t)node * 16 + j4] = pack_h(a);
          } else {
            float v = a.x * Wout[4 * j4] + a.y * Wout[4 * j4 + 1] +
                      a.z * Wout[4 * j4 + 2] + a.w * Wout[4 * j4 + 3];
            v += __shfl_down(v, 8, 16);
            v += __shfl_down(v, 4, 16);
            v += __shfl_down(v, 2, 16);
            v += __shfl_down(v, 1, 16);
            if (j4 == 0) outv[node] = v + bout[0];
          }
        }
      }
      if (!(L == 1 && k == 4)) {
        __threadfence();  // device-scope release of gdst/hb2 stores
        grid.sync();      // phase boundary (covers block sync for Wl reload)
      }
    }
  }
}

// ---------- fallback fused prop + matmul, F=64 (R10, fp16 acc) ----------
template <bool FIRST, bool LAST, bool HEAD>
__launch_bounds__(256)
__global__ void ptag64_k(const int* __restrict__ ptr, const u32* __restrict__ ep,
                         const ushort4* __restrict__ hin, ushort4* __restrict__ hout,
                         const float4* __restrict__ Wk4, const float4* __restrict__ W04,
                         ushort4* __restrict__ acch, const float4* __restrict__ bias4,
                         const float* __restrict__ Wout, const float* __restrict__ bout,
                         float* __restrict__ outv, int n) {
  __shared__ float4 Wl[1024];
  __shared__ float4 tl4[256];
  const float* tl = (const float*)tl4;
  int tid = threadIdx.x;
  for (int i = tid; i < 1024; i += 256) Wl[i] = Wk4[i];
  int gid = blockIdx.x * 256 + tid;
  int node = gid >> 4, j4 = gid & 15, ln = tid >> 4;

  float4 t = make_float4(0.f, 0.f, 0.f, 0.f);
  if (node < n) {
    t = gather<16>(ptr, ep, hin, node, j4);
    if (!LAST) hout[(size_t)node * 16 + j4] = pack_h(t);
  }
  tl4[ln * 16 + (j4 ^ ln)] = t;
  __syncthreads();

  float4 a = make_float4(0.f, 0.f, 0.f, 0.f);
  if (!FIRST && node < n) a = unpack_h(acch[(size_t)node * 16 + j4]);
  mm_acc(tl, Wl, ln, j4, a);
  if (FIRST) {
    __syncthreads();
    for (int i = tid; i < 1024; i += 256) Wl[i] = W04[i];
    float4 own = make_float4(0.f, 0.f, 0.f, 0.f);
    if (node < n) own = unpack_h(hin[(size_t)node * 16 + j4]);
    tl4[ln * 16 + (j4 ^ ln)] = own;
    __syncthreads();
    mm_acc(tl, Wl, ln, j4, a);
  }
  if (node >= n) return;

  if (LAST) {
    float4 b = bias4[j4];
    a.x += b.x; a.y += b.y; a.z += b.z; a.w += b.w;
    a.x = (a.x >= 0.f) ? a.x : 0.01f * a.x;
    a.y = (a.y >= 0.f) ? a.y : 0.01f * a.y;
    a.z = (a.z >= 0.f) ? a.z : 0.01f * a.z;
    a.w = (a.w >= 0.f) ? a.w : 0.01f * a.w;
    if (HEAD) {
      float v = a.x * Wout[4 * j4] + a.y * Wout[4 * j4 + 1] +
                a.z * Wout[4 * j4 + 2] + a.w * Wout[4 * j4 + 3];
      v += __shfl_down(v, 8, 16);
      v += __shfl_down(v, 4, 16);
      v += __shfl_down(v, 2, 16);
      v += __shfl_down(v, 1, 16);
      if (j4 == 0) outv[node] = v + bout[0];
    } else {
      hout[(size_t)node * 16 + j4] = pack_h(a);
    }
  } else {
    acch[(size_t)node * 16 + j4] = pack_h(a);
  }
}

// ---------- fused prop + matmul, layer 1: F_in=16 (4 lanes/node) ----------
template <bool FIRST, bool LAST>
__launch_bounds__(256)
__global__ void ptag16_k(const int* __restrict__ ptr, const u32* __restrict__ ep,
                         const ushort4* __restrict__ hin, ushort4* __restrict__ hout,
                         const float4* __restrict__ Wk4, const float4* __restrict__ W04,
                         ushort4* __restrict__ acch, const float4* __restrict__ bias4,
                         ushort4* __restrict__ outbuf, int n) {
  __shared__ float4 Wl[256];
  __shared__ float4 W0l[FIRST ? 256 : 1];
  __shared__ float4 tl4[64 * 5];
  const float* tl = (const float*)tl4;
  int tid = threadIdx.x;
  Wl[tid] = Wk4[tid];
  if (FIRST) W0l[tid] = W04[tid];
  int gid = blockIdx.x * 256 + tid;
  int node = gid >> 2, q = tid & 3, ln = tid >> 2;

  float4 t = make_float4(0.f, 0.f, 0.f, 0.f);
  if (node < n) {
    t = gather<4>(ptr, ep, hin, node, q);
    if (!LAST) hout[(size_t)node * 4 + q] = pack_h(t);
  }
  tl4[ln * 5 + q] = t;
  __syncthreads();

  float4 a[4];
#pragma unroll
  for (int c = 0; c < 4; ++c) a[c] = make_float4(0.f, 0.f, 0.f, 0.f);
  if (!FIRST && node < n) {
#pragma unroll
    for (int c = 0; c < 4; ++c) a[c] = unpack_h(acch[(size_t)node * 16 + 4 * q + c]);
  }
#pragma unroll 4
  for (int i = 0; i < 16; ++i) {
    float tv = tl[ln * 20 + i];
#pragma unroll
    for (int c = 0; c < 4; ++c) {
      float4 wv = Wl[i * 16 + 4 * q + c];
      a[c].x = fmaf(tv, wv.x, a[c].x); a[c].y = fmaf(tv, wv.y, a[c].y);
      a[c].z = fmaf(tv, wv.z, a[c].z); a[c].w = fmaf(tv, wv.w, a[c].w);
    }
  }
  if (FIRST) {
    __syncthreads();
    float4 own = make_float4(0.f, 0.f, 0.f, 0.f);
    if (node < n) own = unpack_h(hin[(size_t)node * 4 + q]);
    tl4[ln * 5 + q] = own;
    __syncthreads();
#pragma unroll 4
    for (int i = 0; i < 16; ++i) {
      float tv = tl[ln * 20 + i];
#pragma unroll
      for (int c = 0; c < 4; ++c) {
        float4 wv = W0l[i * 16 + 4 * q + c];
        a[c].x = fmaf(tv, wv.x, a[c].x); a[c].y = fmaf(tv, wv.y, a[c].y);
        a[c].z = fmaf(tv, wv.z, a[c].z); a[c].w = fmaf(tv, wv.w, a[c].w);
      }
    }
  }
  if (node >= n) return;

  if (LAST) {
#pragma unroll
    for (int c = 0; c < 4; ++c) {
      float4 b = bias4[4 * q + c];
      a[c].x += b.x; a[c].y += b.y; a[c].z += b.z; a[c].w += b.w;
      a[c].x = (a[c].x >= 0.f) ? a[c].x : 0.01f * a[c].x;
      a[c].y = (a[c].y >= 0.f) ? a[c].y : 0.01f * a[c].y;
      a[c].z = (a[c].z >= 0.f) ? a[c].z : 0.01f * a[c].z;
      a[c].w = (a[c].w >= 0.f) ? a[c].w : 0.01f * a[c].w;
      outbuf[(size_t)node * 16 + 4 * q + c] = pack_h(a[c]);
    }
  } else {
#pragma unroll
    for (int c = 0; c < 4; ++c) acch[(size_t)node * 16 + 4 * q + c] = pack_h(a[c]);
  }
}

extern "C" void kernel_launch(void* const* d_in, const int* in_sizes, int n_in,
                              void* d_out, int out_size, void* d_ws, size_t ws_size,
                              hipStream_t stream) {
  const float* x    = (const float*)d_in[0];
  const int*   ei   = (const int*)d_in[1];
  const float* ew   = (const float*)d_in[2];
  const float* W1   = (const float*)d_in[4];
  const float* b1   = (const float*)d_in[5];
  const float* W2   = (const float*)d_in[6];
  const float* b2   = (const float*)d_in[7];
  const float* Wout = (const float*)d_in[8];
  const float* bout = (const float*)d_in[9];
  float* out = (float*)d_out;

  const int N = in_sizes[0] / 16;
  const int E = in_sizes[2];
  const int* src = ei;
  const int* dst = ei + E;

  char* ws = (char*)d_ws;
  size_t off = 0;
  auto alloc = [&](size_t bytes) {
    char* p = ws + off;
    off = (off + bytes + 255) & ~(size_t)255;
    return p;
  };
  u64*     pack = (u64*)alloc((size_t)N * 8);
  float*   dinv = (float*)alloc((size_t)N * 4);
  int*     ptr  = (int*)alloc(((size_t)N + 1) * 4);
  int*     bsum = (int*)alloc(4096);
  int*     rank = (int*)alloc((size_t)E * 4);
  u32*     ep   = (u32*)alloc((size_t)E * 4);                // packed 4B edges
  ushort4* xh   = (ushort4*)alloc((size_t)N * 16 * 2);       // N x 16 fp16
  ushort4* hb0  = (ushort4*)alloc((size_t)N * 64 * 2);       // t ping
  ushort4* hb1  = (ushort4*)alloc((size_t)N * 64 * 2);       // t pong
  ushort4* hb2  = (ushort4*)alloc((size_t)N * 64 * 2);       // layer outputs
  ushort4* acch = (ushort4*)alloc((size_t)N * 64 * 2);       // fp16 acc (layer1/fallback)

  hipMemsetAsync(pack, 0, (size_t)N * 8, stream);

  int gE = (E + 255) / 256;
  int gN = (N + 255) / 256;
  degcount_k<<<gE, 256, 0, stream>>>(dst, ew, pack, rank, E, (const float4*)x, xh, N * 4);
  scan_blocks<<<gN, 256, 0, stream>>>(pack, dinv, ptr, bsum, N);
  scan_sums<<<1, 512, 0, stream>>>(bsum, gN);
  scan_add<<<gN, 256, 0, stream>>>(ptr, bsum, N, E);
  fill_k<<<gE, 256, 0, stream>>>(src, dst, ew, dinv, ptr, rank, ep, E);

  int g4  = (N * 4 + 255) / 256;   // layer-1 fused (4 lanes/node)
  int g16 = (N * 16 + 255) / 256;  // fallback F=64 fused

  auto W1k = [&](int k) { return (const float4*)(W1 + (size_t)k * 1024); };
  auto W2k = [&](int l, int k) { return (const float4*)(W2 + ((size_t)l * 5 + k) * 4096); };

  // ---- Layer 1 (16 -> 64): acc in acch, t ping-pong hb0/hb1, h1 -> hb2 ----
  ptag16_k<true,  false><<<g4, 256, 0, stream>>>(ptr, ep, xh,  hb0, W1k(1), W1k(0), acch, nullptr, nullptr, N);
  ptag16_k<false, false><<<g4, 256, 0, stream>>>(ptr, ep, hb0, hb1, W1k(2), nullptr, acch, nullptr, nullptr, N);
  ptag16_k<false, false><<<g4, 256, 0, stream>>>(ptr, ep, hb1, hb0, W1k(3), nullptr, acch, nullptr, nullptr, N);
  ptag16_k<false, true ><<<g4, 256, 0, stream>>>(ptr, ep, hb0, nullptr, W1k(4), nullptr, acch,
                                                 (const float4*)b1, hb2, N);

  // ---- Layers 2+3 + head: persistent cooperative kernel (occupancy-gated) ----
  int maxB4 = 0, maxB5 = 0, maxB7 = 0;
  (void)hipOccupancyMaxActiveBlocksPerMultiprocessor(&maxB4, mega_k<4>, 256, 0);
  (void)hipOccupancyMaxActiveBlocksPerMultiprocessor(&maxB5, mega_k<5>, 256, 0);
  (void)hipOccupancyMaxActiveBlocksPerMultiprocessor(&maxB7, mega_k<7>, 256, 0);
  void* fn = nullptr;
  int grid = 0;
  if ((long)maxB4 * 256 * 16 * 4 >= (long)N) {
    fn = (void*)mega_k<4>; grid = maxB4 * 256;
  } else if ((long)maxB5 * 256 * 16 * 5 >= (long)N) {
    fn = (void*)mega_k<5>; grid = maxB5 * 256;
  } else if ((long)maxB7 * 256 * 16 * 7 >= (long)N) {
    fn = (void*)mega_k<7>; grid = maxB7 * 256;
  }

  if (fn) {
    const int* ptrA = ptr; const u32* epA = ep;
    ushort4 *h0A = hb0, *h1A = hb1, *h2A = hb2;
    const float *W2A = W2, *b2A = b2, *WoA = Wout, *boA = bout;
    float* outA = out; int nA = N;
    void* args[] = {&ptrA, &epA, &h0A, &h1A, &h2A, &W2A, &b2A, &WoA, &boA, &outA, &nA};
    hipLaunchCooperativeKernel(fn, dim3(grid), dim3(256), args, 0, stream);
  } else {
    // fallback: R10's proven dispatch sequence
    ptag64_k<true,  false, false><<<g16, 256, 0, stream>>>(ptr, ep, hb2, hb0, W2k(0,1), W2k(0,0), acch,
                                                           nullptr, nullptr, nullptr, nullptr, N);
    ptag64_k<false, false, false><<<g16, 256, 0, stream>>>(ptr, ep, hb0, hb1, W2k(0,2), nullptr, acch,
                                                           nullptr, nullptr, nullptr, nullptr, N);
    ptag64_k<false, false, false><<<g16, 256, 0, stream>>>(ptr, ep, hb1, hb0, W2k(0,3), nullptr, acch,
                                                           nullptr, nullptr, nullptr, nullptr, N);
    ptag64_k<false, true,  false><<<g16, 256, 0, stream>>>(ptr, ep, hb0, hb2, W2k(0,4), nullptr, acch,
                                                           (const float4*)b2, nullptr, nullptr, nullptr, N);
    ptag64_k<true,  false, false><<<g16, 256, 0, stream>>>(ptr, ep, hb2, hb0, W2k(1,1), W2k(1,0), acch,
                                                           nullptr, nullptr, nullptr, nullptr, N);
    ptag64_k<false, false, false><<<g16, 256, 0, stream>>>(ptr, ep, hb0, hb1, W2k(1,2), nullptr, acch,
                                                           nullptr, nullptr, nullptr, nullptr, N);
    ptag64_k<false, false, false><<<g16, 256, 0, stream>>>(ptr, ep, hb1, hb0, W2k(1,3), nullptr, acch,
                                                           nullptr, nullptr, nullptr, nullptr, N);
    ptag64_k<false, true,  true ><<<g16, 256, 0, stream>>>(ptr, ep, hb0, nullptr, W2k(1,4), nullptr, acch,
                                                           (const float4*)(b2 + 64), Wout, bout, out, N);
  }
}